// Round 6
// baseline (11459.039 us; speedup 1.0000x reference)
//
#include <hip/hip_runtime.h>

#define L_ 18
#define H_ 1024
#define NH_ 8
#define HD_ 256
#define FF_ 4096
#define HOR_ 50
#define PRE_ 968
#define B_ 8
#define AD_ 32
#define TPAD_ 1024   // padded KV length (968 prefix + 50 suffix + 6 pad)
#define MROWS_ 400   // B*HOR
#define MPAD_ 512

typedef float f32x4 __attribute__((ext_vector_type(4)));
typedef short s16x4 __attribute__((ext_vector_type(4)));
typedef short s16x8 __attribute__((ext_vector_type(8)));
typedef unsigned short u16x8 __attribute__((ext_vector_type(8)));

__device__ __forceinline__ unsigned short f2bf(float f) {
  unsigned u = __float_as_uint(f);
  u += 0x7FFFu + ((u >> 16) & 1u);   // RTNE (finite inputs)
  return (unsigned short)(u >> 16);
}
__device__ __forceinline__ float bf2f(unsigned short h) {
  return __uint_as_float(((unsigned)h) << 16);
}
__device__ __forceinline__ float wave_sum(float v) {
#pragma unroll
  for (int o = 32; o > 0; o >>= 1) v += __shfl_xor(v, o);
  return v;
}

// ---------------------------------------------------------------- time embedding
__global__ __launch_bounds__(256) void emb_k(const float* __restrict__ ts, float* __restrict__ emb) {
  int b = blockIdx.x, tid = threadIdx.x;
  float t = ts[b];
  for (int j = tid; j < 512; j += 256) {
    float ang = 1570.7963267948966f * expf((float)j * (-6.907755278982137f / 511.0f)) * t;
    emb[(size_t)b * H_ + j] = sinf(ang);
    emb[(size_t)b * H_ + 512 + j] = cosf(ang);
  }
}

// ---------------------------------------------------------------- [8,1024]@[1024,1024] (+bias,+silu)
__global__ __launch_bounds__(256) void gemm8_k(const float* __restrict__ A8, const float* __restrict__ W,
                                               const float* __restrict__ bias, float* __restrict__ out,
                                               int act) {
  __shared__ float a_s[8 * 1024];
  __shared__ float red[4][8][64];
  int tid = threadIdx.x;
  for (int i = tid; i < 8 * 1024; i += 256) a_s[i] = A8[i];
  __syncthreads();
  int nl = tid & 63, kg = tid >> 6;
  int n = blockIdx.x * 64 + nl;
  float acc[8];
#pragma unroll
  for (int m = 0; m < 8; m++) acc[m] = 0.f;
  for (int k = kg * 256; k < kg * 256 + 256; k++) {
    float wv = W[(size_t)k * 1024 + n];
#pragma unroll
    for (int m = 0; m < 8; m++) acc[m] += a_s[m * 1024 + k] * wv;
  }
#pragma unroll
  for (int m = 0; m < 8; m++) red[kg][m][nl] = acc[m];
  __syncthreads();
  if (kg == 0) {
#pragma unroll
    for (int m = 0; m < 8; m++) {
      float v = red[0][m][nl] + red[1][m][nl] + red[2][m][nl] + red[3][m][nl];
      if (bias) v += bias[n];
      if (act) v = v / (1.f + expf(-v));
      out[(size_t)m * 1024 + n] = v;
    }
  }
}

// ---------------------------------------------------------------- all 72 adaLN cond GEMMs in one grid
__global__ __launch_bounds__(256) void gates_k(const float* __restrict__ cond,
                                               const float* __restrict__ w0, const float* __restrict__ w1,
                                               const float* __restrict__ w2, const float* __restrict__ w3,
                                               float* __restrict__ gates) {
  __shared__ float a_s[8 * 1024];
  __shared__ float red[4][8][64];
  int tid = threadIdx.x;
  for (int i = tid; i < 8 * 1024; i += 256) a_s[i] = cond[i];
  __syncthreads();
  int z = blockIdx.z, layer = blockIdx.y;
  const float* W = (z == 0 ? w0 : z == 1 ? w1 : z == 2 ? w2 : w3) + (size_t)layer * H_ * H_;
  float* out = gates + ((size_t)(z * L_ + layer) * 8) * H_;
  int nl = tid & 63, kg = tid >> 6;
  int n = blockIdx.x * 64 + nl;
  float acc[8];
#pragma unroll
  for (int m = 0; m < 8; m++) acc[m] = 0.f;
  for (int k = kg * 256; k < kg * 256 + 256; k++) {
    float wv = W[(size_t)k * 1024 + n];
#pragma unroll
    for (int m = 0; m < 8; m++) acc[m] += a_s[m * 1024 + k] * wv;
  }
#pragma unroll
  for (int m = 0; m < 8; m++) red[kg][m][nl] = acc[m];
  __syncthreads();
  if (kg == 0) {
#pragma unroll
    for (int m = 0; m < 8; m++)
      out[(size_t)m * 1024 + n] = red[0][m][nl] + red[1][m][nl] + red[2][m][nl] + red[3][m][nl];
  }
}

// ---------------------------------------------------------------- pad-mask -> per-batch valid counts
__global__ void offs_k(const unsigned char* __restrict__ mask, int* __restrict__ offs) {
  __shared__ int cnt[8];
  __shared__ int mod4;
  int tid = threadIdx.x;
  if (tid < 8) cnt[tid] = 0;
  if (tid == 8) mod4 = 0;
  __syncthreads();
  for (int i = tid; i < B_ * PRE_; i += 256) {
    unsigned char v = mask[i];
    if (v) {
      atomicAdd(&cnt[i / PRE_], 1);
      if (i & 3) atomicAdd(&mod4, 1);
    }
  }
  __syncthreads();
  if (tid < 8) offs[tid] = (mod4 == 0) ? cnt[tid] * 4 : cnt[tid];
}

// ---------------------------------------------------------------- h = x_t @ action_in_w + b  (pad rows = 0)
__global__ __launch_bounds__(256) void action_in_k(const float* __restrict__ xt, const float* __restrict__ Wi,
                                                   const float* __restrict__ bi, float* __restrict__ h) {
  int idx = blockIdx.x * 256 + threadIdx.x;
  int m = idx >> 10, n = idx & 1023;
  float v = 0.f;
  if (m < MROWS_) {
    const float* xr = xt + (size_t)m * AD_;
#pragma unroll
    for (int k = 0; k < AD_; k++) v += xr[k] * Wi[(size_t)k * H_ + n];
    v += bi[n];
  }
  h[idx] = v;
}

// ---------------------------------------------------------------- AdaRMSNorm -> bf16 (pad rows = 0)
__global__ __launch_bounds__(256) void ada_k(const float* __restrict__ X, const float* __restrict__ nw,
                                             const float* __restrict__ sc, unsigned short* __restrict__ Y) {
  int m = blockIdx.x, tid = threadIdx.x;
  size_t base = (size_t)m * H_;
  if (m >= MROWS_) {
#pragma unroll
    for (int j = 0; j < 4; j++) Y[base + tid * 4 + j] = 0;
    return;
  }
  f32x4 x = *(const f32x4*)(X + base + tid * 4);
  float ss = x[0] * x[0] + x[1] * x[1] + x[2] * x[2] + x[3] * x[3];
  __shared__ float r4[4];
  float wsv = wave_sum(ss);
  if ((tid & 63) == 0) r4[tid >> 6] = wsv;
  __syncthreads();
  float rs = rsqrtf((r4[0] + r4[1] + r4[2] + r4[3]) * (1.f / 1024.f) + 1e-6f);
  int b = m / HOR_;
#pragma unroll
  for (int j = 0; j < 4; j++) {
    int n = tid * 4 + j;
    Y[base + n] = f2bf(x[j] * rs * (1.f + nw[n]) * (1.f + sc[(size_t)b * H_ + n]));
  }
}

// ================================================================ MFMA GEMM (16x16x32)
// A bf16 [512][lda]; W f32 staged to LDS bf16 (transposed, padded).
// MODE 0=QKV split-K partials (Ntot 2560); MODE 1=WO full-K fused gated-residual -> f32;
// MODE 2=UPGATE dual-strip, direct t=gelu(g)*u bf16; MODE 3=DOWN full-K fused gated-residual -> f32.
// grid (nstrips, NS, MS); 512 thr = 8 waves.
#define KSTEP_ 128
#define LST_ 132   // LDS k-stride in shorts

template <int MODE, int NS, int MS>
__global__ __launch_bounds__(512) void gemmS_k(const unsigned short* __restrict__ A, int lda, int Ksz,
                                               const float* __restrict__ W0, const float* __restrict__ W1,
                                               const float* __restrict__ W2,
                                               float* __restrict__ outF, unsigned short* __restrict__ outB,
                                               const float* __restrict__ prev, const float* __restrict__ gatev) {
  constexpr int NCOL = (MODE == 2) ? 64 : 32;
  constexpr int NF = NCOL / 16;
  constexpr int RPW = 64 / MS;     // rows per wave
  constexpr int MFC = RPW / 16;    // m-fragments per wave
  const int tid = threadIdx.x;
  const int wv = tid >> 6, l = tid & 63;
  const int lr = l & 15, lk = (l >> 4) << 2;   // 2*lk = 8*kg
  const int n0 = blockIdx.x * 32;
  const int kz = blockIdx.y;
  const int KC = Ksz / NS;
  const int kbase = kz * KC;
  const int m0 = (int)blockIdx.z * (512 / MS) + wv * RPW;

  const float* Wg;
  const float* Wu = nullptr;
  int ldw, wcol;
  if (MODE == 0) {
    if (n0 < 2048)      { Wg = W0; ldw = 2048; wcol = n0; }
    else if (n0 < 2304) { Wg = W1; ldw = 256;  wcol = n0 - 2048; }
    else                { Wg = W2; ldw = 256;  wcol = n0 - 2304; }
  } else if (MODE == 1) {
    Wg = W0; ldw = 1024; wcol = n0;
  } else if (MODE == 2) {
    Wg = W0; Wu = W1; ldw = 4096; wcol = n0;
  } else {
    Wg = W0; ldw = 1024; wcol = n0;
  }

  __shared__ unsigned short Wt[2][NCOL][LST_];
  const int pr = tid >> 3;          // 0..63: k-pair index within KSTEP
  const int c0 = (tid & 7) * 4;     // col group within strip

  f32x4 acc[MFC][NF];
#pragma unroll
  for (int a = 0; a < MFC; a++)
#pragma unroll
    for (int b = 0; b < NF; b++) acc[a][b] = (f32x4){0.f, 0.f, 0.f, 0.f};

  const int niter = KC / KSTEP_;
  f32x4 pa0, pa1, pb0, pb1;

#define LOADW(IT)                                                                     \
  {                                                                                   \
    size_t kk_ = (size_t)(kbase + (IT) * KSTEP_ + 2 * pr);                            \
    pa0 = *(const f32x4*)(Wg + kk_ * ldw + wcol + c0);                                \
    pa1 = *(const f32x4*)(Wg + (kk_ + 1) * ldw + wcol + c0);                          \
    if (MODE == 2) {                                                                  \
      pb0 = *(const f32x4*)(Wu + kk_ * ldw + wcol + c0);                              \
      pb1 = *(const f32x4*)(Wu + (kk_ + 1) * ldw + wcol + c0);                        \
    }                                                                                 \
  }
#define STOREW(BUF)                                                                   \
  {                                                                                   \
    _Pragma("unroll") for (int j_ = 0; j_ < 4; j_++) {                                \
      unsigned v_ = (unsigned)f2bf(pa0[j_]) | ((unsigned)f2bf(pa1[j_]) << 16);        \
      *(unsigned*)&Wt[BUF][c0 + j_][2 * pr] = v_;                                     \
      if (MODE == 2) {                                                                \
        unsigned u_ = (unsigned)f2bf(pb0[j_]) | ((unsigned)f2bf(pb1[j_]) << 16);      \
        *(unsigned*)&Wt[BUF][32 + c0 + j_][2 * pr] = u_;                              \
      }                                                                               \
    }                                                                                 \
  }

  LOADW(0);
  STOREW(0);
  __syncthreads();

  for (int it = 0; it < niter; ++it) {
    if (it + 1 < niter) LOADW(it + 1);
    const int cur = it & 1;
    const int kb = kbase + it * KSTEP_;
#pragma unroll
    for (int s = 0; s < 4; s++) {   // K=32 per step
      s16x8 bfr[NF];
#pragma unroll
      for (int nf = 0; nf < NF; nf++) {
        s16x4 b0 = *(const s16x4*)&Wt[cur][nf * 16 + lr][s * 32 + 2 * lk];
        s16x4 b1 = *(const s16x4*)&Wt[cur][nf * 16 + lr][s * 32 + 2 * lk + 4];
#pragma unroll
        for (int j = 0; j < 4; j++) { bfr[nf][j] = b0[j]; bfr[nf][4 + j] = b1[j]; }
      }
#pragma unroll
      for (int mf = 0; mf < MFC; mf++) {
        s16x8 a = *(const s16x8*)(A + (size_t)(m0 + mf * 16 + lr) * lda + kb + s * 32 + 2 * lk);
#pragma unroll
        for (int nf = 0; nf < NF; nf++)
          acc[mf][nf] = __builtin_amdgcn_mfma_f32_16x16x32_bf16(a, bfr[nf], acc[mf][nf], 0, 0, 0);
      }
    }
    if (it + 1 < niter) STOREW((it + 1) & 1);
    __syncthreads();
  }
#undef LOADW
#undef STOREW

  if (MODE == 2) {
#pragma unroll
    for (int mf = 0; mf < MFC; mf++)
#pragma unroll
      for (int nf = 0; nf < 2; nf++)
#pragma unroll
        for (int r = 0; r < 4; r++) {
          int row = m0 + mf * 16 + lk + r;
          if (row >= MROWS_) continue;
          int col = n0 + nf * 16 + lr;
          float g = acc[mf][nf][r];
          float u = acc[mf][nf + 2][r];
          g = 0.5f * g * (1.f + tanhf(0.7978845608028654f * (g + 0.044715f * g * g * g)));
          outB[(size_t)row * 4096 + col] = f2bf(g * u);
        }
  } else if (MODE == 1 || MODE == 3) {
#pragma unroll
    for (int mf = 0; mf < MFC; mf++)
#pragma unroll
      for (int nf = 0; nf < NF; nf++)
#pragma unroll
        for (int r = 0; r < 4; r++) {
          int row = m0 + mf * 16 + lk + r;
          if (row >= MROWS_) continue;
          int bb = row / HOR_;
          int col = n0 + nf * 16 + lr;
          size_t idx = (size_t)row * 1024 + col;
          outF[idx] = prev[idx] + gatev[(size_t)bb * 1024 + col] * acc[mf][nf][r];
        }
  } else {  // MODE 0: split-K partials
#pragma unroll
    for (int mf = 0; mf < MFC; mf++)
#pragma unroll
      for (int nf = 0; nf < NF; nf++)
#pragma unroll
        for (int r = 0; r < 4; r++) {
          int row = m0 + mf * 16 + lk + r;
          if (row >= MROWS_) continue;
          int col = n0 + nf * 16 + lr;
          outF[((size_t)kz * MPAD_ + row) * 2560 + col] = acc[mf][nf][r];
        }
  }
}

// ---------------------------------------------------------------- all-layer prefix convert: K row-major, V transposed
__global__ __launch_bounds__(256) void prefixAll_k(const float* __restrict__ pk, const float* __restrict__ pv,
                                                   unsigned short* __restrict__ Kf_all,
                                                   unsigned short* __restrict__ Vt_all) {
  int b = blockIdx.y, t0 = blockIdx.x * 64, layer = blockIdx.z, tid = threadIdx.x;
  unsigned short* Kf = Kf_all + (size_t)layer * B_ * TPAD_ * HD_;
  unsigned short* Vt = Vt_all + (size_t)layer * B_ * HD_ * TPAD_;
  __shared__ unsigned short vt[256][72];
  const float* kp = pk + ((size_t)(b * L_ + layer)) * PRE_ * HD_;
  const float* vp = pv + ((size_t)(b * L_ + layer)) * PRE_ * HD_;
  for (int i = 0; i < 64; i++) {
    int t = t0 + i;
    float kv = 0.f, vv = 0.f;
    if (t < PRE_) {
      kv = kp[(size_t)t * HD_ + tid];
      vv = vp[(size_t)t * HD_ + tid];
    }
    Kf[((size_t)b * TPAD_ + t) * HD_ + tid] = f2bf(kv);  // suffix rows rewritten per layer by flashF2
    vt[tid][i] = f2bf(vv);
  }
  __syncthreads();
#pragma unroll
  for (int p = 0; p < 4; p++) {
    int d = p * 64 + (tid >> 2);
    int c0 = (tid & 3) * 16;
    u16x8 v0, v1;
#pragma unroll
    for (int j = 0; j < 8; j++) { v0[j] = vt[d][c0 + j]; v1[j] = vt[d][c0 + 8 + j]; }
    size_t dst = ((size_t)(b * HD_ + d)) * TPAD_ + t0 + c0;
    *(u16x8*)(Vt + dst) = v0;
    *(u16x8*)(Vt + dst + 8) = v1;
  }
}

// ---------------------------------------------------------------- fused flash: QKV-part reduce + RoPE + suffix KV
// staging + flash attention, one kernel -> attb. grid (B, 4 rg, NH) [b fastest => per-b KV stays on one XCD].
// 256 thr = 4 waves. Block handles 16 q-rows (rg*16..+16) of head h, batch b.
// Wave w: QK^T over t-chunk [256w,256w+256) -> local softmax -> P tile (LDS); then PV over d-slice
// [64w,64w+64) across ALL t with per-chunk accs, rescaled in epilogue. Suffix K/V written to GLOBAL
// Kf/Vt (identical duplicated writes across the 32 blocks of a batch -- deterministic).
__global__ __launch_bounds__(256) void flashF2_k(const float* __restrict__ part, const int* __restrict__ offs,
                                                 unsigned short* __restrict__ Kf, unsigned short* __restrict__ Vt,
                                                 unsigned short* __restrict__ attb) {
  const int b = blockIdx.x, rg = blockIdx.y, h = blockIdx.z;
  const int tid = threadIdx.x, w = tid >> 6, l = tid & 63;
  const int lr = l & 15, kg = l >> 4;

  __shared__ __align__(16) unsigned short Pl[4][16][264];
  __shared__ float mlS[4][16][2];

  // ---- stage suffix V (t in [968,1024)): thread = dim d, transposed writes
  {
    int d = tid;
    unsigned short* vdst = Vt + ((size_t)(b * HD_ + d)) * TPAD_ + PRE_;
#pragma unroll 4
    for (int j = 0; j < 56; j++) {
      float v = 0.f;
      if (j < HOR_) {
        int m = b * HOR_ + j;
        v = part[((size_t)0 * MPAD_ + m) * 2560 + 2304 + d] + part[((size_t)1 * MPAD_ + m) * 2560 + 2304 + d];
      }
      vdst[j] = f2bf(v);
    }
  }
  // ---- stage suffix K (rope'd): 2 rows per iteration, 128 threads/row handle (dd, dd+128)
  {
    int dd = tid & 127;
    float inv = expf((float)dd * (-9.210340371976184f / 128.0f));
#pragma unroll 2
    for (int jj = 0; jj < 28; jj++) {
      int j = jj * 2 + (tid >> 7);   // 0..55
      unsigned short k1 = 0, k2 = 0;
      if (j < HOR_) {
        int m = b * HOR_ + j;
        const float* p0 = part + ((size_t)0 * MPAD_ + m) * 2560 + 2048;
        const float* p1 = part + ((size_t)1 * MPAD_ + m) * 2560 + 2048;
        float x1 = p0[dd] + p1[dd];
        float x2 = p0[dd + 128] + p1[dd + 128];
        float a = (float)(offs[b] + j) * inv;
        float cc = cosf(a), sn = sinf(a);
        k1 = f2bf(x1 * cc - x2 * sn);
        k2 = f2bf(x2 * cc + x1 * sn);
      }
      unsigned short* kdst = Kf + ((size_t)b * TPAD_ + PRE_ + j) * HD_;
      kdst[dd] = k1;
      kdst[dd + 128] = k2;
    }
  }
  // ---- Q: reduce 2 parts + RoPE, in-register (lane lr owns q-row s = rg*16+lr)
  const int srow = rg * 16 + lr;
  const int mq = b * HOR_ + srow;     // may index garbage rows (s>=50): finite, discarded
  const float pos = (float)(offs[b] + srow);
  s16x8 afr[8];
  {
    f32x4 qv[16];
    const float* q0 = part + ((size_t)0 * MPAD_ + mq) * 2560 + h * HD_;
    const float* q1 = part + ((size_t)1 * MPAD_ + mq) * 2560 + h * HD_;
#pragma unroll
    for (int js = 0; js < 8; js++) {
      int d0 = js * 32 + 8 * kg;
      qv[2 * js] = *(const f32x4*)(q0 + d0) + *(const f32x4*)(q1 + d0);
      qv[2 * js + 1] = *(const f32x4*)(q0 + d0 + 4) + *(const f32x4*)(q1 + d0 + 4);
    }
#pragma unroll
    for (int jp = 0; jp < 4; jp++)
#pragma unroll
      for (int e = 0; e < 8; e++) {
        int dd = jp * 32 + 8 * kg + e;
        float x1 = qv[2 * jp + (e >> 2)][e & 3];
        float x2 = qv[2 * (jp + 4) + (e >> 2)][e & 3];
        float a = pos * expf((float)dd * (-9.210340371976184f / 128.0f));
        float cc = cosf(a), sn = sinf(a);
        afr[jp][e] = (short)f2bf(x1 * cc - x2 * sn);
        afr[jp + 4][e] = (short)f2bf(x2 * cc + x1 * sn);
      }
  }
  __syncthreads();   // suffix K/V visible block-wide

  // ---- QK^T: wave w over t-chunk [256w, +256)
  const int t0 = w * 256;
  f32x4 sc[16];
#pragma unroll
  for (int nf = 0; nf < 16; nf++) sc[nf] = (f32x4){0.f, 0.f, 0.f, 0.f};
  const unsigned short* kb = Kf + ((size_t)b * TPAD_ + t0) * HD_;
#pragma unroll
  for (int js = 0; js < 8; js++) {
#pragma unroll
    for (int nf = 0; nf < 16; nf++) {
      s16x8 bv = *(const s16x8*)(kb + (size_t)(nf * 16 + lr) * HD_ + js * 32 + 8 * kg);
      sc[nf] = __builtin_amdgcn_mfma_f32_16x16x32_bf16(afr[js], bv, sc[nf], 0, 0, 0);
    }
  }
  // ---- scale + mask + chunk-local softmax (rows = rg*16 + 4kg + r)
  float mx[4] = {-3.0e38f, -3.0e38f, -3.0e38f, -3.0e38f};
#pragma unroll
  for (int nf = 0; nf < 16; nf++) {
    int t = t0 + nf * 16 + lr;
#pragma unroll
    for (int r = 0; r < 4; r++) {
      int srw = rg * 16 + 4 * kg + r;
      float v = sc[nf][r] * 0.0625f;
      if (t >= PRE_ && (t - PRE_) > srw) v = -1e9f;
      sc[nf][r] = v;
      mx[r] = fmaxf(mx[r], v);
    }
  }
#pragma unroll
  for (int o = 8; o > 0; o >>= 1)
#pragma unroll
    for (int r = 0; r < 4; r++) mx[r] = fmaxf(mx[r], __shfl_xor(mx[r], o));
  float ls[4] = {0.f, 0.f, 0.f, 0.f};
#pragma unroll
  for (int nf = 0; nf < 16; nf++)
#pragma unroll
    for (int r = 0; r < 4; r++) {
      float p = expf(sc[nf][r] - mx[r]);
      sc[nf][r] = p;
      ls[r] += p;
    }
#pragma unroll
  for (int o = 8; o > 0; o >>= 1)
#pragma unroll
    for (int r = 0; r < 4; r++) ls[r] += __shfl_xor(ls[r], o);
#pragma unroll
  for (int nf = 0; nf < 16; nf++)
#pragma unroll
    for (int r = 0; r < 4; r++) Pl[w][4 * kg + r][nf * 16 + lr] = f2bf(sc[nf][r]);
  if (lr == 0) {
#pragma unroll
    for (int r = 0; r < 4; r++) {
      mlS[w][4 * kg + r][0] = mx[r];
      mlS[w][4 * kg + r][1] = ls[r];
    }
  }
  __syncthreads();
  // ---- PV: wave w computes d-slice [64w, +64) over ALL t, per-chunk accumulators
  f32x4 o4[4][4];   // [wz][nf]
#pragma unroll
  for (int a = 0; a < 4; a++)
#pragma unroll
    for (int c = 0; c < 4; c++) o4[a][c] = (f32x4){0.f, 0.f, 0.f, 0.f};
#pragma unroll
  for (int wz = 0; wz < 4; wz++) {
#pragma unroll
    for (int ti = 0; ti < 256; ti += 32) {
      s16x8 a = *(const s16x8*)&Pl[wz][lr][ti + 8 * kg];
#pragma unroll
      for (int nf = 0; nf < 4; nf++) {
        s16x8 bv = *(const s16x8*)(Vt + ((size_t)(b * HD_ + w * 64 + nf * 16 + lr)) * TPAD_ + wz * 256 + ti + 8 * kg);
        o4[wz][nf] = __builtin_amdgcn_mfma_f32_16x16x32_bf16(a, bv, o4[wz][nf], 0, 0, 0);
      }
    }
  }
  // ---- epilogue: global softmax rescale + write
#pragma unroll
  for (int r = 0; r < 4; r++) {
    int row = 4 * kg + r;
    int s = rg * 16 + row;
    if (s >= HOR_) continue;
    float M = fmaxf(fmaxf(mlS[0][row][0], mlS[1][row][0]), fmaxf(mlS[2][row][0], mlS[3][row][0]));
    float w4[4], L = 0.f;
#pragma unroll
    for (int wz = 0; wz < 4; wz++) {
      w4[wz] = expf(mlS[wz][row][0] - M);
      L += w4[wz] * mlS[wz][row][1];
    }
    float invL = 1.f / L;
#pragma unroll
    for (int nf = 0; nf < 4; nf++) {
      float o = w4[0] * o4[0][nf][r] + w4[1] * o4[1][nf][r] + w4[2] * o4[2][nf][r] + w4[3] * o4[3][nf][r];
      attb[((size_t)(b * HOR_ + s)) * 2048 + h * HD_ + w * 64 + nf * 16 + lr] = f2bf(o * invL);
    }
  }
}

// ---------------------------------------------------------------- out = normedF @ action_out_w + b
__global__ __launch_bounds__(256) void fout_k(const unsigned short* __restrict__ nf, const float* __restrict__ Wo,
                                              const float* __restrict__ bo, float* __restrict__ out) {
  int m = blockIdx.x, tid = threadIdx.x;
  int n = tid & 31, kg = tid >> 5;
  float acc = 0.f;
  for (int k = kg * 128; k < kg * 128 + 128; k++)
    acc += bf2f(nf[(size_t)m * H_ + k]) * Wo[(size_t)k * AD_ + n];
  __shared__ float red[8][32];
  red[kg][n] = acc;
  __syncthreads();
  if (kg == 0) {
    float v = 0.f;
#pragma unroll
    for (int g = 0; g < 8; g++) v += red[g][n];
    out[(size_t)m * AD_ + n] = v + bo[n];
  }
}

// ================================================================ host
extern "C" void kernel_launch(void* const* d_in, const int* in_sizes, int n_in,
                              void* d_out, int out_size, void* d_ws, size_t ws_size,
                              hipStream_t stream) {
  const float* prefix_keys   = (const float*)d_in[0];
  const float* prefix_values = (const float*)d_in[1];
  const float* x_t           = (const float*)d_in[2];
  const float* timestep      = (const float*)d_in[3];
  const unsigned char* pad_mask = (const unsigned char*)d_in[4];
  const float* action_in_w   = (const float*)d_in[5];
  const float* action_in_b   = (const float*)d_in[6];
  const float* action_out_w  = (const float*)d_in[7];
  const float* action_out_b  = (const float*)d_in[8];
  const float* tmlp_in_w     = (const float*)d_in[9];
  const float* tmlp_in_b     = (const float*)d_in[10];
  const float* tmlp_out_w    = (const float*)d_in[11];
  const float* tmlp_out_b    = (const float*)d_in[12];
  const float* w_q    = (const float*)d_in[13];
  const float* w_k    = (const float*)d_in[14];
  const float* w_v    = (const float*)d_in[15];
  const float* w_o    = (const float*)d_in[16];
  const float* w_gate = (const float*)d_in[17];
  const float* w_up   = (const float*)d_in[18];
  const float* w_down = (const float*)d_in[19];
  const float* in_norm_w    = (const float*)d_in[20];
  const float* in_scale_w   = (const float*)d_in[21];
  const float* in_gate_w    = (const float*)d_in[22];
  const float* post_norm_w  = (const float*)d_in[23];
  const float* post_scale_w = (const float*)d_in[24];
  const float* post_gate_w  = (const float*)d_in[25];
  const float* fnorm_w       = (const float*)d_in[26];
  const float* fnorm_scale_w = (const float*)d_in[27];

  char* wsp = (char*)d_ws;
  auto alloc = [&](size_t bytes) { void* p = (void*)wsp; wsp += (bytes + 255) & ~(size_t)255; return p; };

  float* emb0   = (float*)alloc((size_t)8 * H_ * 4);
  float* emb1   = (float*)alloc((size_t)8 * H_ * 4);
  float* cond   = (float*)alloc((size_t)8 * H_ * 4);
  float* fscale = (float*)alloc((size_t)8 * H_ * 4);
  float* gates  = (float*)alloc((size_t)4 * L_ * 8 * H_ * 4);
  int*   offs   = (int*)alloc(64);
  float* hbuf   = (float*)alloc((size_t)MPAD_ * H_ * 4);
  float* h1buf  = (float*)alloc((size_t)MPAD_ * H_ * 4);
  unsigned short* normed  = (unsigned short*)alloc((size_t)MPAD_ * H_ * 2);
  unsigned short* normed2 = (unsigned short*)alloc((size_t)MPAD_ * H_ * 2);
  unsigned short* Kf_all  = (unsigned short*)alloc((size_t)L_ * B_ * TPAD_ * HD_ * 2);
  unsigned short* Vt_all  = (unsigned short*)alloc((size_t)L_ * B_ * HD_ * TPAD_ * 2);
  unsigned short* attb    = (unsigned short*)alloc((size_t)MPAD_ * 2048 * 2);
  unsigned short* t_buf   = (unsigned short*)alloc((size_t)MPAD_ * FF_ * 2);
  float* qkvpart = (float*)alloc((size_t)2 * MPAD_ * 2560 * 4);

  // attb pad rows (400..511) never written by flashF2: zero once (stays zero all layers)
  hipMemsetAsync(attb + (size_t)MROWS_ * 2048, 0, (size_t)(MPAD_ - MROWS_) * 2048 * 2, stream);

  emb_k<<<8, 256, 0, stream>>>(timestep, emb0);
  gemm8_k<<<16, 256, 0, stream>>>(emb0, tmlp_in_w, tmlp_in_b, emb1, 1);
  gemm8_k<<<16, 256, 0, stream>>>(emb1, tmlp_out_w, tmlp_out_b, cond, 1);
  gemm8_k<<<16, 256, 0, stream>>>(cond, fnorm_scale_w, nullptr, fscale, 0);
  gates_k<<<dim3(16, L_, 4), 256, 0, stream>>>(cond, in_scale_w, in_gate_w, post_scale_w, post_gate_w, gates);
  offs_k<<<1, 256, 0, stream>>>(pad_mask, offs);
  action_in_k<<<(MPAD_ * H_) / 256, 256, 0, stream>>>(x_t, action_in_w, action_in_b, hbuf);
  prefixAll_k<<<dim3(16, B_, L_), 256, 0, stream>>>(prefix_keys, prefix_values, Kf_all, Vt_all);
  ada_k<<<MPAD_, 256, 0, stream>>>(hbuf, in_norm_w, gates + 0, normed);  // layer-0 in_scale = gates[0][0]

  for (int i = 0; i < L_; i++) {
    const float* wq_i = w_q + (size_t)i * H_ * 2048;
    const float* wk_i = w_k + (size_t)i * H_ * HD_;
    const float* wv_i = w_v + (size_t)i * H_ * HD_;
    const float* wo_i = w_o + (size_t)i * 2048 * H_;
    const float* wg_i = w_gate + (size_t)i * H_ * FF_;
    const float* wu_i = w_up + (size_t)i * H_ * FF_;
    const float* wd_i = w_down + (size_t)i * FF_ * H_;
    const float* g_in_gate    = gates + ((size_t)(1 * L_ + i) * 8) * H_;
    const float* g_post_scale = gates + ((size_t)(2 * L_ + i) * 8) * H_;
    const float* g_post_gate  = gates + ((size_t)(3 * L_ + i) * 8) * H_;
    unsigned short* Kf_l = Kf_all + (size_t)i * B_ * TPAD_ * HD_;
    unsigned short* Vt_l = Vt_all + (size_t)i * B_ * HD_ * TPAD_;

    gemmS_k<0, 2, 2><<<dim3(80, 2, 2), 512, 0, stream>>>(normed, H_, H_, wq_i, wk_i, wv_i,
                                                         qkvpart, nullptr, nullptr, nullptr);
    flashF2_k<<<dim3(B_, 4, NH_), 256, 0, stream>>>(qkvpart, offs, Kf_l, Vt_l, attb);
    gemmS_k<1, 1, 4><<<dim3(32, 1, 4), 512, 0, stream>>>(attb, 2048, 2048, wo_i, nullptr, nullptr,
                                                         h1buf, nullptr, hbuf, g_in_gate);
    ada_k<<<MPAD_, 256, 0, stream>>>(h1buf, post_norm_w + (size_t)i * H_, g_post_scale, normed2);
    gemmS_k<2, 1, 2><<<dim3(128, 1, 2), 512, 0, stream>>>(normed2, H_, H_, wg_i, wu_i, nullptr,
                                                          nullptr, t_buf, nullptr, nullptr);
    gemmS_k<3, 1, 4><<<dim3(32, 1, 4), 512, 0, stream>>>(t_buf, FF_, FF_, wd_i, nullptr, nullptr,
                                                         hbuf, nullptr, h1buf, g_post_gate);
    const float* nw_next = (i + 1 < L_) ? in_norm_w + (size_t)(i + 1) * H_ : fnorm_w;
    const float* sc_next = (i + 1 < L_) ? gates + ((size_t)(0 * L_ + i + 1) * 8) * H_ : fscale;
    ada_k<<<MPAD_, 256, 0, stream>>>(hbuf, nw_next, sc_next, normed);
  }

  fout_k<<<MROWS_, 256, 0, stream>>>(normed, action_out_w, action_out_b, (float*)d_out);
}

// Round 7
// 8054.945 us; speedup vs baseline: 1.4226x; 1.4226x over previous
//
#include <hip/hip_runtime.h>
#include <hip/hip_cooperative_groups.h>

namespace cg = cooperative_groups;

#define L_ 18
#define H_ 1024
#define NH_ 8
#define HD_ 256
#define FF_ 4096
#define HOR_ 50
#define PRE_ 968
#define B_ 8
#define AD_ 32
#define TPAD_ 1024
#define MROWS_ 400
#define MPAD_ 512
#define KSTEP_ 128
#define LST_ 132

typedef float f32x4 __attribute__((ext_vector_type(4)));
typedef short s16x4 __attribute__((ext_vector_type(4)));
typedef short s16x8 __attribute__((ext_vector_type(8)));
typedef unsigned short u16x8 __attribute__((ext_vector_type(8)));

__device__ __forceinline__ unsigned short f2bf(float f) {
  unsigned u = __float_as_uint(f);
  u += 0x7FFFu + ((u >> 16) & 1u);
  return (unsigned short)(u >> 16);
}
__device__ __forceinline__ float bf2f(unsigned short h) {
  return __uint_as_float(((unsigned)h) << 16);
}
__device__ __forceinline__ float wave_sum(float v) {
#pragma unroll
  for (int o = 32; o > 0; o >>= 1) v += __shfl_xor(v, o);
  return v;
}

// ---------------------------------------------------------------- prologue kernels (unchanged, validated)
__global__ __launch_bounds__(256) void emb_k(const float* __restrict__ ts, float* __restrict__ emb) {
  int b = blockIdx.x, tid = threadIdx.x;
  float t = ts[b];
  for (int j = tid; j < 512; j += 256) {
    float ang = 1570.7963267948966f * expf((float)j * (-6.907755278982137f / 511.0f)) * t;
    emb[(size_t)b * H_ + j] = sinf(ang);
    emb[(size_t)b * H_ + 512 + j] = cosf(ang);
  }
}

__global__ __launch_bounds__(256) void gemm8_k(const float* __restrict__ A8, const float* __restrict__ W,
                                               const float* __restrict__ bias, float* __restrict__ out,
                                               int act) {
  __shared__ float a_s[8 * 1024];
  __shared__ float red[4][8][64];
  int tid = threadIdx.x;
  for (int i = tid; i < 8 * 1024; i += 256) a_s[i] = A8[i];
  __syncthreads();
  int nl = tid & 63, kg = tid >> 6;
  int n = blockIdx.x * 64 + nl;
  float acc[8];
#pragma unroll
  for (int m = 0; m < 8; m++) acc[m] = 0.f;
  for (int k = kg * 256; k < kg * 256 + 256; k++) {
    float wv = W[(size_t)k * 1024 + n];
#pragma unroll
    for (int m = 0; m < 8; m++) acc[m] += a_s[m * 1024 + k] * wv;
  }
#pragma unroll
  for (int m = 0; m < 8; m++) red[kg][m][nl] = acc[m];
  __syncthreads();
  if (kg == 0) {
#pragma unroll
    for (int m = 0; m < 8; m++) {
      float v = red[0][m][nl] + red[1][m][nl] + red[2][m][nl] + red[3][m][nl];
      if (bias) v += bias[n];
      if (act) v = v / (1.f + expf(-v));
      out[(size_t)m * 1024 + n] = v;
    }
  }
}

__global__ __launch_bounds__(256) void gates_k(const float* __restrict__ cond,
                                               const float* __restrict__ w0, const float* __restrict__ w1,
                                               const float* __restrict__ w2, const float* __restrict__ w3,
                                               float* __restrict__ gates) {
  __shared__ float a_s[8 * 1024];
  __shared__ float red[4][8][64];
  int tid = threadIdx.x;
  for (int i = tid; i < 8 * 1024; i += 256) a_s[i] = cond[i];
  __syncthreads();
  int z = blockIdx.z, layer = blockIdx.y;
  const float* W = (z == 0 ? w0 : z == 1 ? w1 : z == 2 ? w2 : w3) + (size_t)layer * H_ * H_;
  float* out = gates + ((size_t)(z * L_ + layer) * 8) * H_;
  int nl = tid & 63, kg = tid >> 6;
  int n = blockIdx.x * 64 + nl;
  float acc[8];
#pragma unroll
  for (int m = 0; m < 8; m++) acc[m] = 0.f;
  for (int k = kg * 256; k < kg * 256 + 256; k++) {
    float wv = W[(size_t)k * 1024 + n];
#pragma unroll
    for (int m = 0; m < 8; m++) acc[m] += a_s[m * 1024 + k] * wv;
  }
#pragma unroll
  for (int m = 0; m < 8; m++) red[kg][m][nl] = acc[m];
  __syncthreads();
  if (kg == 0) {
#pragma unroll
    for (int m = 0; m < 8; m++)
      out[(size_t)m * 1024 + n] = red[0][m][nl] + red[1][m][nl] + red[2][m][nl] + red[3][m][nl];
  }
}

__global__ void offs_k(const unsigned char* __restrict__ mask, int* __restrict__ offs) {
  __shared__ int cnt[8];
  __shared__ int mod4;
  int tid = threadIdx.x;
  if (tid < 8) cnt[tid] = 0;
  if (tid == 8) mod4 = 0;
  __syncthreads();
  for (int i = tid; i < B_ * PRE_; i += 256) {
    unsigned char v = mask[i];
    if (v) {
      atomicAdd(&cnt[i / PRE_], 1);
      if (i & 3) atomicAdd(&mod4, 1);
    }
  }
  __syncthreads();
  if (tid < 8) offs[tid] = (mod4 == 0) ? cnt[tid] * 4 : cnt[tid];
}

__global__ __launch_bounds__(256) void action_in_k(const float* __restrict__ xt, const float* __restrict__ Wi,
                                                   const float* __restrict__ bi, float* __restrict__ h) {
  int idx = blockIdx.x * 256 + threadIdx.x;
  int m = idx >> 10, n = idx & 1023;
  float v = 0.f;
  if (m < MROWS_) {
    const float* xr = xt + (size_t)m * AD_;
#pragma unroll
    for (int k = 0; k < AD_; k++) v += xr[k] * Wi[(size_t)k * H_ + n];
    v += bi[n];
  }
  h[idx] = v;
}

__global__ __launch_bounds__(256) void ada_k(const float* __restrict__ X, const float* __restrict__ nw,
                                             const float* __restrict__ sc, unsigned short* __restrict__ Y) {
  int m = blockIdx.x, tid = threadIdx.x;
  size_t base = (size_t)m * H_;
  if (m >= MROWS_) {
#pragma unroll
    for (int j = 0; j < 4; j++) Y[base + tid * 4 + j] = 0;
    return;
  }
  f32x4 x = *(const f32x4*)(X + base + tid * 4);
  float ss = x[0] * x[0] + x[1] * x[1] + x[2] * x[2] + x[3] * x[3];
  __shared__ float r4[4];
  float wsv = wave_sum(ss);
  if ((tid & 63) == 0) r4[tid >> 6] = wsv;
  __syncthreads();
  float rs = rsqrtf((r4[0] + r4[1] + r4[2] + r4[3]) * (1.f / 1024.f) + 1e-6f);
  int b = m / HOR_;
#pragma unroll
  for (int j = 0; j < 4; j++) {
    int n = tid * 4 + j;
    Y[base + n] = f2bf(x[j] * rs * (1.f + nw[n]) * (1.f + sc[(size_t)b * H_ + n]));
  }
}

__global__ __launch_bounds__(256) void prefixAll_k(const float* __restrict__ pk, const float* __restrict__ pv,
                                                   unsigned short* __restrict__ Kf_all,
                                                   unsigned short* __restrict__ Vt_all) {
  int b = blockIdx.y, t0 = blockIdx.x * 64, layer = blockIdx.z, tid = threadIdx.x;
  unsigned short* Kf = Kf_all + (size_t)layer * B_ * TPAD_ * HD_;
  unsigned short* Vt = Vt_all + (size_t)layer * B_ * HD_ * TPAD_;
  __shared__ unsigned short vt[256][72];
  const float* kp = pk + ((size_t)(b * L_ + layer)) * PRE_ * HD_;
  const float* vp = pv + ((size_t)(b * L_ + layer)) * PRE_ * HD_;
  for (int i = 0; i < 64; i++) {
    int t = t0 + i;
    float kv = 0.f, vv = 0.f;
    if (t < PRE_) {
      kv = kp[(size_t)t * HD_ + tid];
      vv = vp[(size_t)t * HD_ + tid];
    }
    Kf[((size_t)b * TPAD_ + t) * HD_ + tid] = f2bf(kv);
    vt[tid][i] = f2bf(vv);
  }
  __syncthreads();
#pragma unroll
  for (int p = 0; p < 4; p++) {
    int d = p * 64 + (tid >> 2);
    int c0 = (tid & 3) * 16;
    u16x8 v0, v1;
#pragma unroll
    for (int j = 0; j < 8; j++) { v0[j] = vt[d][c0 + j]; v1[j] = vt[d][c0 + 8 + j]; }
    size_t dst = ((size_t)(b * HD_ + d)) * TPAD_ + t0 + c0;
    *(u16x8*)(Vt + dst) = v0;
    *(u16x8*)(Vt + dst + 8) = v1;
  }
}

// ================================================================ gemm core (validated round-5 inner loop)
// STRIPW=16: only tid<256 stage. DUAL: Wu staged into cols 32..63. Full-K (NITER iters of 128).
template <int STRIPW, int MFC, bool DUAL, int NITER, int NF>
__device__ __forceinline__ void gemm_core(const unsigned short* __restrict__ A, int lda,
                                          const float* __restrict__ Wg, const float* __restrict__ Wu,
                                          int ldw, int wcol, int m0,
                                          unsigned short* __restrict__ Wt, f32x4 (&acc)[MFC][NF]) {
  const int tid = threadIdx.x;
  const int l = tid & 63;
  const int lr = l & 15, lk = (l >> 4) << 2;
  constexpr bool N16 = (STRIPW == 16);
  const int pr = N16 ? (tid >> 2) : (tid >> 3);
  const int c0 = N16 ? ((tid & 3) * 4) : ((tid & 7) * 4);
  const bool act = N16 ? (tid < 256) : true;

  f32x4 pa0, pa1, pb0, pb1;
  auto LOADW = [&](int IT) {
    if (act) {
      size_t kk = (size_t)IT * KSTEP_ + 2 * pr;
      pa0 = *(const f32x4*)(Wg + kk * ldw + wcol + c0);
      pa1 = *(const f32x4*)(Wg + (kk + 1) * ldw + wcol + c0);
      if (DUAL) {
        pb0 = *(const f32x4*)(Wu + kk * ldw + wcol + c0);
        pb1 = *(const f32x4*)(Wu + (kk + 1) * ldw + wcol + c0);
      }
    }
  };
  auto STOREW = [&](int BUF) {
    if (act) {
#pragma unroll
      for (int j = 0; j < 4; j++) {
        unsigned v = (unsigned)f2bf(pa0[j]) | ((unsigned)f2bf(pa1[j]) << 16);
        *(unsigned*)&Wt[(size_t)((BUF * 64) + c0 + j) * LST_ + 2 * pr] = v;
        if (DUAL) {
          unsigned u = (unsigned)f2bf(pb0[j]) | ((unsigned)f2bf(pb1[j]) << 16);
          *(unsigned*)&Wt[(size_t)((BUF * 64) + 32 + c0 + j) * LST_ + 2 * pr] = u;
        }
      }
    }
  };

  LOADW(0);
  STOREW(0);
  __syncthreads();
  for (int it = 0; it < NITER; ++it) {
    if (it + 1 < NITER) LOADW(it + 1);
    const int cur = it & 1;
    const int kb = it * KSTEP_;
#pragma unroll
    for (int s = 0; s < 4; s++) {
      s16x8 bfr[NF];
#pragma unroll
      for (int nf = 0; nf < NF; nf++) {
        const unsigned short* wp = &Wt[(size_t)((cur * 64) + nf * 16 + lr) * LST_ + s * 32 + 2 * lk];
        s16x4 b0 = *(const s16x4*)wp;
        s16x4 b1 = *(const s16x4*)(wp + 4);
#pragma unroll
        for (int j = 0; j < 4; j++) { bfr[nf][j] = b0[j]; bfr[nf][4 + j] = b1[j]; }
      }
#pragma unroll
      for (int mf = 0; mf < MFC; mf++) {
        s16x8 a = *(const s16x8*)(A + (size_t)(m0 + mf * 16 + lr) * lda + kb + s * 32 + 2 * lk);
#pragma unroll
        for (int nf = 0; nf < NF; nf++)
          acc[mf][nf] = __builtin_amdgcn_mfma_f32_16x16x32_bf16(a, bfr[nf], acc[mf][nf], 0, 0, 0);
      }
    }
    if (it + 1 < NITER) STOREW((it + 1) & 1);
    __syncthreads();
  }
}

// ================================================================ persistent cooperative mega-kernel
// 256 blocks x 512 threads. 18 layers, 8 grid-syncs each. All phase math = validated round-5 kernels.
__global__ __launch_bounds__(512, 2) void mega_k(
    unsigned short* __restrict__ normed, unsigned short* __restrict__ normed2,
    float* __restrict__ hbuf, float* __restrict__ h1buf,
    unsigned short* __restrict__ qkv, unsigned short* __restrict__ q_r,
    unsigned short* __restrict__ Kf_all, unsigned short* __restrict__ Vt_all,
    unsigned short* __restrict__ attb, unsigned short* __restrict__ t_buf,
    const float* __restrict__ gates, const int* __restrict__ offs,
    const float* __restrict__ w_q, const float* __restrict__ w_k,
    const float* __restrict__ w_v, const float* __restrict__ w_o,
    const float* __restrict__ w_gate, const float* __restrict__ w_up,
    const float* __restrict__ w_down,
    const float* __restrict__ in_norm_w, const float* __restrict__ post_norm_w,
    const float* __restrict__ fnorm_w, const float* __restrict__ fscale,
    const float* __restrict__ action_out_w, const float* __restrict__ action_out_b,
    float* __restrict__ out) {
  cg::grid_group grid = cg::this_grid();
  const int bid = blockIdx.x;
  const int tid = threadIdx.x;
  const int wv = tid >> 6, l = tid & 63;
  const int lr = l & 15, kg = l >> 4, lk = kg << 2;

  __shared__ union {
    unsigned short wt[2 * 64 * LST_];                                  // gemm staging
    struct { unsigned short P[8][16][136]; float ml[8][16][2]; } fl;   // flash
    struct { float r4[2][4]; } ada;
    struct { float red[2][8][32]; } fo;
  } sm;

  auto ada_phase = [&](const float* X, const float* nw, const float* scv, unsigned short* Y) {
    const int half = tid >> 8, t = tid & 255;
    const int m = bid * 2 + half;
    size_t base = (size_t)m * H_;
    f32x4 x = (f32x4){0.f, 0.f, 0.f, 0.f};
    if (m < MROWS_) x = *(const f32x4*)(X + base + t * 4);
    float ss = x[0] * x[0] + x[1] * x[1] + x[2] * x[2] + x[3] * x[3];
    float wsv = wave_sum(ss);
    if ((t & 63) == 0) sm.ada.r4[half][t >> 6] = wsv;
    __syncthreads();
    float rs = rsqrtf((sm.ada.r4[half][0] + sm.ada.r4[half][1] + sm.ada.r4[half][2] + sm.ada.r4[half][3]) *
                          (1.f / 1024.f) + 1e-6f);
    if (m < MROWS_) {
      int bb = m / HOR_;
#pragma unroll
      for (int j = 0; j < 4; j++) {
        int n = t * 4 + j;
        Y[base + n] = f2bf(x[j] * rs * (1.f + nw[n]) * (1.f + scv[(size_t)bb * H_ + n]));
      }
    } else {
#pragma unroll
      for (int j = 0; j < 4; j++) Y[base + t * 4 + j] = 0;
    }
    __syncthreads();
  };

  for (int layer = 0; layer < L_; ++layer) {
    const float* wq_i = w_q + (size_t)layer * H_ * 2048;
    const float* wk_i = w_k + (size_t)layer * H_ * HD_;
    const float* wv_i = w_v + (size_t)layer * H_ * HD_;
    const float* wo_i = w_o + (size_t)layer * 2048 * H_;
    const float* wg_i = w_gate + (size_t)layer * H_ * FF_;
    const float* wu_i = w_up + (size_t)layer * H_ * FF_;
    const float* wd_i = w_down + (size_t)layer * FF_ * H_;
    const float* g_in_gate = gates + ((size_t)(1 * L_ + layer) * 8) * H_;
    const float* g_post_scale = gates + ((size_t)(2 * L_ + layer) * 8) * H_;
    const float* g_post_gate = gates + ((size_t)(3 * L_ + layer) * 8) * H_;
    unsigned short* Kf = Kf_all + (size_t)layer * B_ * TPAD_ * HD_;
    unsigned short* Vt = Vt_all + (size_t)layer * B_ * HD_ * TPAD_;

    // ---------------- A: QKV GEMM (full-K) -> qkv bf16 [512][2560]
    if (bid < 160) {
      const int strip = bid % 80, mh = bid / 80;
      const int n0 = strip * 32;
      const float* Wsel;
      int ldw, wcol;
      if (n0 < 2048)      { Wsel = wq_i; ldw = 2048; wcol = n0; }
      else if (n0 < 2304) { Wsel = wk_i; ldw = 256;  wcol = n0 - 2048; }
      else                { Wsel = wv_i; ldw = 256;  wcol = n0 - 2304; }
      const int m0 = mh * 256 + wv * 32;
      f32x4 acc[2][2];
#pragma unroll
      for (int a = 0; a < 2; a++)
#pragma unroll
        for (int b = 0; b < 2; b++) acc[a][b] = (f32x4){0.f, 0.f, 0.f, 0.f};
      gemm_core<32, 2, false, 8, 2>(normed, 1024, Wsel, nullptr, ldw, wcol, m0, sm.wt, acc);
#pragma unroll
      for (int mf = 0; mf < 2; mf++)
#pragma unroll
        for (int nf = 0; nf < 2; nf++)
#pragma unroll
          for (int r = 0; r < 4; r++) {
            int row = m0 + mf * 16 + lk + r;
            int col = n0 + nf * 16 + lr;
            qkv[(size_t)row * 2560 + col] = f2bf(acc[mf][nf][r]);
          }
    }
    grid.sync();

    // ---------------- B: rope + scatter (half-block per (b,s) row)
    {
      const int half = tid >> 8, t = tid & 255;
      const int item = bid * 2 + half;
      const int b = item >> 6, s = item & 63;
      if (s >= HOR_) {
#pragma unroll
        for (int h = 0; h < NH_; h++) q_r[(((size_t)(b * NH_ + h)) * 64 + s) * HD_ + t] = 0;
      } else {
        const unsigned short* row = qkv + (size_t)(b * HOR_ + s) * 2560;
        const float pos = (float)(offs[b] + s);
#pragma unroll
        for (int it = 0; it < 4; it++) {
          int p = t + it * 256;
          int h = p >> 7, dd = p & 127;
          float inv = expf((float)dd * (-9.210340371976184f / 128.0f));
          float a = pos * inv;
          float cc = cosf(a), sn = sinf(a);
          float x1 = bf2f(row[h * HD_ + dd]), x2 = bf2f(row[h * HD_ + dd + 128]);
          unsigned short* qo = q_r + (((size_t)(b * NH_ + h)) * 64 + s) * HD_;
          qo[dd] = f2bf(x1 * cc - x2 * sn);
          qo[dd + 128] = f2bf(x2 * cc + x1 * sn);
        }
        if (t < 128) {
          int dd = t;
          float inv = expf((float)dd * (-9.210340371976184f / 128.0f));
          float a = pos * inv;
          float cc = cosf(a), sn = sinf(a);
          float x1 = bf2f(row[2048 + dd]), x2 = bf2f(row[2048 + dd + 128]);
          unsigned short* ko = Kf + ((size_t)b * TPAD_ + PRE_ + s) * HD_;
          ko[dd] = f2bf(x1 * cc - x2 * sn);
          ko[dd + 128] = f2bf(x2 * cc + x1 * sn);
        }
        Vt[((size_t)(b * HD_ + t)) * TPAD_ + PRE_ + s] = row[2304 + t];
      }
    }
    grid.sync();

    // ---------------- C: flash attention (block = (b,rg,h); 8 waves x 128-token chunks)
    {
      const int b = bid >> 5, rg = (bid >> 3) & 3, h = bid & 7;
      const int t0 = wv * 128;
      const unsigned short* qbase = q_r + (((size_t)(b * NH_ + h)) * 64 + rg * 16 + lr) * HD_;
      s16x8 afr[8];
#pragma unroll
      for (int js = 0; js < 8; js++) afr[js] = *(const s16x8*)(qbase + js * 32 + 8 * kg);
      f32x4 sc[8];
#pragma unroll
      for (int nf = 0; nf < 8; nf++) sc[nf] = (f32x4){0.f, 0.f, 0.f, 0.f};
      const unsigned short* kb = Kf + ((size_t)b * TPAD_ + t0) * HD_;
#pragma unroll
      for (int js = 0; js < 8; js++)
#pragma unroll
        for (int nf = 0; nf < 8; nf++) {
          s16x8 bv = *(const s16x8*)(kb + (size_t)(nf * 16 + lr) * HD_ + js * 32 + 8 * kg);
          sc[nf] = __builtin_amdgcn_mfma_f32_16x16x32_bf16(afr[js], bv, sc[nf], 0, 0, 0);
        }
      float mx[4] = {-3.0e38f, -3.0e38f, -3.0e38f, -3.0e38f};
#pragma unroll
      for (int nf = 0; nf < 8; nf++) {
        int t = t0 + nf * 16 + lr;
#pragma unroll
        for (int r = 0; r < 4; r++) {
          int srw = rg * 16 + 4 * kg + r;
          float v = sc[nf][r] * 0.0625f;
          if (t >= PRE_ && (t - PRE_) > srw) v = -1e9f;
          sc[nf][r] = v;
          mx[r] = fmaxf(mx[r], v);
        }
      }
#pragma unroll
      for (int o = 8; o > 0; o >>= 1)
#pragma unroll
        for (int r = 0; r < 4; r++) mx[r] = fmaxf(mx[r], __shfl_xor(mx[r], o));
      float ls[4] = {0.f, 0.f, 0.f, 0.f};
#pragma unroll
      for (int nf = 0; nf < 8; nf++)
#pragma unroll
        for (int r = 0; r < 4; r++) {
          float p = expf(sc[nf][r] - mx[r]);
          sc[nf][r] = p;
          ls[r] += p;
        }
#pragma unroll
      for (int o = 8; o > 0; o >>= 1)
#pragma unroll
        for (int r = 0; r < 4; r++) ls[r] += __shfl_xor(ls[r], o);
#pragma unroll
      for (int nf = 0; nf < 8; nf++)
#pragma unroll
        for (int r = 0; r < 4; r++) sm.fl.P[wv][4 * kg + r][nf * 16 + lr] = f2bf(sc[nf][r]);
      if (lr == 0) {
#pragma unroll
        for (int r = 0; r < 4; r++) {
          sm.fl.ml[wv][4 * kg + r][0] = mx[r];
          sm.fl.ml[wv][4 * kg + r][1] = ls[r];
        }
      }
      __syncthreads();
      f32x4 o4[8][2];
#pragma unroll
      for (int a = 0; a < 8; a++)
#pragma unroll
        for (int c = 0; c < 2; c++) o4[a][c] = (f32x4){0.f, 0.f, 0.f, 0.f};
#pragma unroll
      for (int wz = 0; wz < 8; wz++)
#pragma unroll
        for (int ti = 0; ti < 128; ti += 32) {
          s16x8 a = *(const s16x8*)&sm.fl.P[wz][lr][ti + 8 * kg];
#pragma unroll
          for (int nf = 0; nf < 2; nf++) {
            s16x8 bv = *(const s16x8*)(Vt + ((size_t)(b * HD_ + wv * 32 + nf * 16 + lr)) * TPAD_ +
                                       wz * 128 + ti + 8 * kg);
            o4[wz][nf] = __builtin_amdgcn_mfma_f32_16x16x32_bf16(a, bv, o4[wz][nf], 0, 0, 0);
          }
        }
#pragma unroll
      for (int r = 0; r < 4; r++) {
        int row = 4 * kg + r;
        int s = rg * 16 + row;
        if (s < HOR_) {
          float M = -3.0e38f;
#pragma unroll
          for (int wz = 0; wz < 8; wz++) M = fmaxf(M, sm.fl.ml[wz][row][0]);
          float w8[8], Lden = 0.f;
#pragma unroll
          for (int wz = 0; wz < 8; wz++) {
            w8[wz] = expf(sm.fl.ml[wz][row][0] - M);
            Lden += w8[wz] * sm.fl.ml[wz][row][1];
          }
          float invL = 1.f / Lden;
#pragma unroll
          for (int nf = 0; nf < 2; nf++) {
            float o = 0.f;
#pragma unroll
            for (int wz = 0; wz < 8; wz++) o += w8[wz] * o4[wz][nf][r];
            attb[((size_t)(b * HOR_ + s)) * 2048 + h * HD_ + wv * 32 + nf * 16 + lr] = f2bf(o * invL);
          }
        }
      }
      __syncthreads();
    }
    grid.sync();

    // ---------------- D: W_o GEMM full-K + gated residual -> h1buf
    {
      const int strip = bid & 63, mq = bid >> 6;
      const int n0 = strip * 16;
      const int m0 = mq * 128 + wv * 16;
      f32x4 acc[1][1];
      acc[0][0] = (f32x4){0.f, 0.f, 0.f, 0.f};
      gemm_core<16, 1, false, 16, 1>(attb, 2048, wo_i, nullptr, 1024, n0, m0, sm.wt, acc);
#pragma unroll
      for (int r = 0; r < 4; r++) {
        int row = m0 + lk + r;
        if (row < MROWS_) {
          int bb = row / HOR_;
          int col = n0 + lr;
          size_t idx = (size_t)row * 1024 + col;
          h1buf[idx] = hbuf[idx] + g_in_gate[(size_t)bb * 1024 + col] * acc[0][0][r];
        }
      }
    }
    grid.sync();

    // ---------------- E: ada(h1) -> normed2
    ada_phase(h1buf, post_norm_w + (size_t)layer * H_, g_post_scale, normed2);
    grid.sync();

    // ---------------- F: upgate dual GEMM -> t_buf = gelu(g)*u
    {
      const int strip = bid & 127, mh = bid >> 7;
      const int n0 = strip * 32;
      const int m0 = mh * 256 + wv * 32;
      f32x4 acc[2][4];
#pragma unroll
      for (int a = 0; a < 2; a++)
#pragma unroll
        for (int b = 0; b < 4; b++) acc[a][b] = (f32x4){0.f, 0.f, 0.f, 0.f};
      gemm_core<32, 2, true, 8, 4>(normed2, 1024, wg_i, wu_i, 4096, n0, m0, sm.wt, acc);
#pragma unroll
      for (int mf = 0; mf < 2; mf++)
#pragma unroll
        for (int nf = 0; nf < 2; nf++)
#pragma unroll
          for (int r = 0; r < 4; r++) {
            int row = m0 + mf * 16 + lk + r;
            if (row < MROWS_) {
              int col = n0 + nf * 16 + lr;
              float g = acc[mf][nf][r];
              float u = acc[mf][nf + 2][r];
              g = 0.5f * g * (1.f + tanhf(0.7978845608028654f * (g + 0.044715f * g * g * g)));
              t_buf[(size_t)row * 4096 + col] = f2bf(g * u);
            }
          }
    }
    grid.sync();

    // ---------------- G: down GEMM full-K + gated residual -> hbuf
    {
      const int strip = bid & 63, mq = bid >> 6;
      const int n0 = strip * 16;
      const int m0 = mq * 128 + wv * 16;
      f32x4 acc[1][1];
      acc[0][0] = (f32x4){0.f, 0.f, 0.f, 0.f};
      gemm_core<16, 1, false, 32, 1>(t_buf, 4096, wd_i, nullptr, 1024, n0, m0, sm.wt, acc);
#pragma unroll
      for (int r = 0; r < 4; r++) {
        int row = m0 + lk + r;
        if (row < MROWS_) {
          int bb = row / HOR_;
          int col = n0 + lr;
          size_t idx = (size_t)row * 1024 + col;
          hbuf[idx] = h1buf[idx] + g_post_gate[(size_t)bb * 1024 + col] * acc[0][0][r];
        }
      }
    }
    grid.sync();

    // ---------------- H: ada(h) -> normed (next layer or final norm)
    {
      const float* nw = (layer + 1 < L_) ? in_norm_w + (size_t)(layer + 1) * H_ : fnorm_w;
      const float* scv = (layer + 1 < L_) ? gates + ((size_t)(layer + 1) * 8) * H_ : fscale;
      ada_phase(hbuf, nw, scv, normed);
    }
    grid.sync();
  }

  // ---------------- fout: out = normed @ action_out_w + b (half-block per row)
  {
    const int half = tid >> 8, t = tid & 255;
    const int m = bid * 2 + half;
    const int n = t & 31, kg2 = t >> 5;
    float a = 0.f;
    if (m < MROWS_) {
      for (int k = kg2 * 128; k < kg2 * 128 + 128; k++)
        a += bf2f(normed[(size_t)m * H_ + k]) * action_out_w[(size_t)k * AD_ + n];
    }
    sm.fo.red[half][kg2][n] = a;
    __syncthreads();
    if (m < MROWS_ && kg2 == 0) {
      float v = 0.f;
#pragma unroll
      for (int g = 0; g < 8; g++) v += sm.fo.red[half][g][n];
      out[(size_t)m * AD_ + n] = v + action_out_b[n];
    }
  }
}

// ================================================================ host
extern "C" void kernel_launch(void* const* d_in, const int* in_sizes, int n_in,
                              void* d_out, int out_size, void* d_ws, size_t ws_size,
                              hipStream_t stream) {
  const float* prefix_keys   = (const float*)d_in[0];
  const float* prefix_values = (const float*)d_in[1];
  const float* x_t           = (const float*)d_in[2];
  const float* timestep      = (const float*)d_in[3];
  const unsigned char* pad_mask = (const unsigned char*)d_in[4];
  const float* action_in_w   = (const float*)d_in[5];
  const float* action_in_b   = (const float*)d_in[6];
  const float* action_out_w  = (const float*)d_in[7];
  const float* action_out_b  = (const float*)d_in[8];
  const float* tmlp_in_w     = (const float*)d_in[9];
  const float* tmlp_in_b     = (const float*)d_in[10];
  const float* tmlp_out_w    = (const float*)d_in[11];
  const float* tmlp_out_b    = (const float*)d_in[12];
  const float* w_q    = (const float*)d_in[13];
  const float* w_k    = (const float*)d_in[14];
  const float* w_v    = (const float*)d_in[15];
  const float* w_o    = (const float*)d_in[16];
  const float* w_gate = (const float*)d_in[17];
  const float* w_up   = (const float*)d_in[18];
  const float* w_down = (const float*)d_in[19];
  const float* in_norm_w    = (const float*)d_in[20];
  const float* in_scale_w   = (const float*)d_in[21];
  const float* in_gate_w    = (const float*)d_in[22];
  const float* post_norm_w  = (const float*)d_in[23];
  const float* post_scale_w = (const float*)d_in[24];
  const float* post_gate_w  = (const float*)d_in[25];
  const float* fnorm_w       = (const float*)d_in[26];
  const float* fnorm_scale_w = (const float*)d_in[27];

  char* wsp = (char*)d_ws;
  auto alloc = [&](size_t bytes) { void* p = (void*)wsp; wsp += (bytes + 255) & ~(size_t)255; return p; };

  float* emb0   = (float*)alloc((size_t)8 * H_ * 4);
  float* emb1   = (float*)alloc((size_t)8 * H_ * 4);
  float* cond   = (float*)alloc((size_t)8 * H_ * 4);
  float* fscale = (float*)alloc((size_t)8 * H_ * 4);
  float* gates  = (float*)alloc((size_t)4 * L_ * 8 * H_ * 4);
  int*   offs   = (int*)alloc(64);
  float* hbuf   = (float*)alloc((size_t)MPAD_ * H_ * 4);
  float* h1buf  = (float*)alloc((size_t)MPAD_ * H_ * 4);
  unsigned short* normed  = (unsigned short*)alloc((size_t)MPAD_ * H_ * 2);
  unsigned short* normed2 = (unsigned short*)alloc((size_t)MPAD_ * H_ * 2);
  unsigned short* qkv     = (unsigned short*)alloc((size_t)MPAD_ * 2560 * 2);
  unsigned short* q_r     = (unsigned short*)alloc((size_t)B_ * NH_ * 64 * HD_ * 2);
  unsigned short* Kf_all  = (unsigned short*)alloc((size_t)L_ * B_ * TPAD_ * HD_ * 2);
  unsigned short* Vt_all  = (unsigned short*)alloc((size_t)L_ * B_ * HD_ * TPAD_ * 2);
  unsigned short* attb    = (unsigned short*)alloc((size_t)MPAD_ * 2048 * 2);
  unsigned short* t_buf   = (unsigned short*)alloc((size_t)MPAD_ * FF_ * 2);
  float* outp = (float*)d_out;

  hipMemsetAsync(attb + (size_t)MROWS_ * 2048, 0, (size_t)(MPAD_ - MROWS_) * 2048 * 2, stream);

  emb_k<<<8, 256, 0, stream>>>(timestep, emb0);
  gemm8_k<<<16, 256, 0, stream>>>(emb0, tmlp_in_w, tmlp_in_b, emb1, 1);
  gemm8_k<<<16, 256, 0, stream>>>(emb1, tmlp_out_w, tmlp_out_b, cond, 1);
  gemm8_k<<<16, 256, 0, stream>>>(cond, fnorm_scale_w, nullptr, fscale, 0);
  gates_k<<<dim3(16, L_, 4), 256, 0, stream>>>(cond, in_scale_w, in_gate_w, post_scale_w, post_gate_w, gates);
  offs_k<<<1, 256, 0, stream>>>(pad_mask, offs);
  action_in_k<<<(MPAD_ * H_) / 256, 256, 0, stream>>>(x_t, action_in_w, action_in_b, hbuf);
  prefixAll_k<<<dim3(16, B_, L_), 256, 0, stream>>>(prefix_keys, prefix_values, Kf_all, Vt_all);
  ada_k<<<MPAD_, 256, 0, stream>>>(hbuf, in_norm_w, gates, normed);  // layer-0 in_scale = gates z=0,l=0

  void* margs[] = {
    (void*)&normed, (void*)&normed2, (void*)&hbuf, (void*)&h1buf, (void*)&qkv, (void*)&q_r,
    (void*)&Kf_all, (void*)&Vt_all, (void*)&attb, (void*)&t_buf, (void*)&gates, (void*)&offs,
    (void*)&w_q, (void*)&w_k, (void*)&w_v, (void*)&w_o, (void*)&w_gate, (void*)&w_up, (void*)&w_down,
    (void*)&in_norm_w, (void*)&post_norm_w, (void*)&fnorm_w, (void*)&fscale,
    (void*)&action_out_w, (void*)&action_out_b, (void*)&outp};
  hipLaunchCooperativeKernel((void*)mega_k, dim3(256), dim3(512), margs, 0, stream);
}

// Round 8
// 5212.668 us; speedup vs baseline: 2.1983x; 1.5453x over previous
//
#include <hip/hip_runtime.h>

#define L_ 18
#define H_ 1024
#define NH_ 8
#define HD_ 256
#define FF_ 4096
#define HOR_ 50
#define PRE_ 968
#define B_ 8
#define AD_ 32
#define TPAD_ 1024
#define MROWS_ 400
#define MPAD_ 512
#define KSTEP_ 128
#define LST_ 132

typedef float f32x4 __attribute__((ext_vector_type(4)));
typedef short s16x4 __attribute__((ext_vector_type(4)));
typedef short s16x8 __attribute__((ext_vector_type(8)));
typedef unsigned short u16x8 __attribute__((ext_vector_type(8)));

__device__ __forceinline__ unsigned short f2bf(float f) {
  unsigned u = __float_as_uint(f);
  u += 0x7FFFu + ((u >> 16) & 1u);
  return (unsigned short)(u >> 16);
}
__device__ __forceinline__ float bf2f(unsigned short h) {
  return __uint_as_float(((unsigned)h) << 16);
}
__device__ __forceinline__ float wave_sum(float v) {
#pragma unroll
  for (int o = 32; o > 0; o >>= 1) v += __shfl_xor(v, o);
  return v;
}

// ---------------------------------------------------------------- time embedding
__global__ __launch_bounds__(256) void emb_k(const float* __restrict__ ts, float* __restrict__ emb) {
  int b = blockIdx.x, tid = threadIdx.x;
  float t = ts[b];
  for (int j = tid; j < 512; j += 256) {
    float ang = 1570.7963267948966f * expf((float)j * (-6.907755278982137f / 511.0f)) * t;
    emb[(size_t)b * H_ + j] = sinf(ang);
    emb[(size_t)b * H_ + 512 + j] = cosf(ang);
  }
}

// ---------------------------------------------------------------- [8,1024]@[1024,1024] (+bias,+silu)
__global__ __launch_bounds__(256) void gemm8_k(const float* __restrict__ A8, const float* __restrict__ W,
                                               const float* __restrict__ bias, float* __restrict__ out,
                                               int act) {
  __shared__ float a_s[8 * 1024];
  __shared__ float red[4][8][64];
  int tid = threadIdx.x;
  for (int i = tid; i < 8 * 1024; i += 256) a_s[i] = A8[i];
  __syncthreads();
  int nl = tid & 63, kg = tid >> 6;
  int n = blockIdx.x * 64 + nl;
  float acc[8];
#pragma unroll
  for (int m = 0; m < 8; m++) acc[m] = 0.f;
  for (int k = kg * 256; k < kg * 256 + 256; k++) {
    float wv = W[(size_t)k * 1024 + n];
#pragma unroll
    for (int m = 0; m < 8; m++) acc[m] += a_s[m * 1024 + k] * wv;
  }
#pragma unroll
  for (int m = 0; m < 8; m++) red[kg][m][nl] = acc[m];
  __syncthreads();
  if (kg == 0) {
#pragma unroll
    for (int m = 0; m < 8; m++) {
      float v = red[0][m][nl] + red[1][m][nl] + red[2][m][nl] + red[3][m][nl];
      if (bias) v += bias[n];
      if (act) v = v / (1.f + expf(-v));
      out[(size_t)m * 1024 + n] = v;
    }
  }
}

// ---------------------------------------------------------------- all 72 adaLN cond GEMMs in one grid
__global__ __launch_bounds__(256) void gates_k(const float* __restrict__ cond,
                                               const float* __restrict__ w0, const float* __restrict__ w1,
                                               const float* __restrict__ w2, const float* __restrict__ w3,
                                               float* __restrict__ gates) {
  __shared__ float a_s[8 * 1024];
  __shared__ float red[4][8][64];
  int tid = threadIdx.x;
  for (int i = tid; i < 8 * 1024; i += 256) a_s[i] = cond[i];
  __syncthreads();
  int z = blockIdx.z, layer = blockIdx.y;
  const float* W = (z == 0 ? w0 : z == 1 ? w1 : z == 2 ? w2 : w3) + (size_t)layer * H_ * H_;
  float* out = gates + ((size_t)(z * L_ + layer) * 8) * H_;
  int nl = tid & 63, kg = tid >> 6;
  int n = blockIdx.x * 64 + nl;
  float acc[8];
#pragma unroll
  for (int m = 0; m < 8; m++) acc[m] = 0.f;
  for (int k = kg * 256; k < kg * 256 + 256; k++) {
    float wv = W[(size_t)k * 1024 + n];
#pragma unroll
    for (int m = 0; m < 8; m++) acc[m] += a_s[m * 1024 + k] * wv;
  }
#pragma unroll
  for (int m = 0; m < 8; m++) red[kg][m][nl] = acc[m];
  __syncthreads();
  if (kg == 0) {
#pragma unroll
    for (int m = 0; m < 8; m++)
      out[(size_t)m * 1024 + n] = red[0][m][nl] + red[1][m][nl] + red[2][m][nl] + red[3][m][nl];
  }
}

// ---------------------------------------------------------------- pad-mask -> per-batch valid counts
__global__ void offs_k(const unsigned char* __restrict__ mask, int* __restrict__ offs) {
  __shared__ int cnt[8];
  __shared__ int mod4;
  int tid = threadIdx.x;
  if (tid < 8) cnt[tid] = 0;
  if (tid == 8) mod4 = 0;
  __syncthreads();
  for (int i = tid; i < B_ * PRE_; i += 256) {
    unsigned char v = mask[i];
    if (v) {
      atomicAdd(&cnt[i / PRE_], 1);
      if (i & 3) atomicAdd(&mod4, 1);
    }
  }
  __syncthreads();
  if (tid < 8) offs[tid] = (mod4 == 0) ? cnt[tid] * 4 : cnt[tid];
}

// ---------------------------------------------------------------- h = x_t @ action_in_w + b  (pad rows = 0)
__global__ __launch_bounds__(256) void action_in_k(const float* __restrict__ xt, const float* __restrict__ Wi,
                                                   const float* __restrict__ bi, float* __restrict__ h) {
  int idx = blockIdx.x * 256 + threadIdx.x;
  int m = idx >> 10, n = idx & 1023;
  float v = 0.f;
  if (m < MROWS_) {
    const float* xr = xt + (size_t)m * AD_;
#pragma unroll
    for (int k = 0; k < AD_; k++) v += xr[k] * Wi[(size_t)k * H_ + n];
    v += bi[n];
  }
  h[idx] = v;
}

// ---------------------------------------------------------------- w2[slot][b][n] = (1+nw[n])*(1+sc[b][n])
// slots: 0..17 = in (layer), 18..35 = post (layer-18), 36 = final
__global__ __launch_bounds__(256) void w2p_k(const float* __restrict__ in_norm_w,
                                             const float* __restrict__ post_norm_w,
                                             const float* __restrict__ fnorm_w,
                                             const float* __restrict__ gates, const float* __restrict__ fscale,
                                             float* __restrict__ w2all) {
  int slot = blockIdx.x, b = blockIdx.y, tid = threadIdx.x;
  const float* nw;
  const float* sc;
  if (slot < 18) {
    nw = in_norm_w + (size_t)slot * 1024;
    sc = gates + ((size_t)(0 * L_ + slot) * 8 + b) * 1024;
  } else if (slot < 36) {
    nw = post_norm_w + (size_t)(slot - 18) * 1024;
    sc = gates + ((size_t)(2 * L_ + (slot - 18)) * 8 + b) * 1024;
  } else {
    nw = fnorm_w;
    sc = fscale + (size_t)b * 1024;
  }
  float* o = w2all + ((size_t)slot * 8 + b) * 1024;
  for (int i = tid; i < 1024; i += 256) o[i] = (1.f + nw[i]) * (1.f + sc[i]);
}

// ---------------------------------------------------------------- layer-0 row sum-of-squares -> ssB part 0
__global__ __launch_bounds__(256) void rowss0_k(const float* __restrict__ hbuf, float* __restrict__ ssB) {
  int m = blockIdx.x, tid = threadIdx.x;
  float ss = 0.f;
  if (m < MROWS_) {
    f32x4 x = *(const f32x4*)(hbuf + (size_t)m * 1024 + tid * 4);
    ss = x[0] * x[0] + x[1] * x[1] + x[2] * x[2] + x[3] * x[3];
  }
  __shared__ float r4[4];
  float wsv = wave_sum(ss);
  if ((tid & 63) == 0) r4[tid >> 6] = wsv;
  __syncthreads();
  if (tid == 0) ssB[m] = r4[0] + r4[1] + r4[2] + r4[3];
  if (tid >= 1 && tid < 64) ssB[(size_t)tid * 512 + m] = 0.f;
}

// ---------------------------------------------------------------- all-layer prefix convert: K row-major, V transposed
__global__ __launch_bounds__(256) void prefixAll_k(const float* __restrict__ pk, const float* __restrict__ pv,
                                                   unsigned short* __restrict__ Kf_all,
                                                   unsigned short* __restrict__ Vt_all) {
  int b = blockIdx.y, t0 = blockIdx.x * 64, layer = blockIdx.z, tid = threadIdx.x;
  unsigned short* Kf = Kf_all + (size_t)layer * B_ * TPAD_ * HD_;
  unsigned short* Vt = Vt_all + (size_t)layer * B_ * HD_ * TPAD_;
  __shared__ unsigned short vt[256][72];
  const float* kp = pk + ((size_t)(b * L_ + layer)) * PRE_ * HD_;
  const float* vp = pv + ((size_t)(b * L_ + layer)) * PRE_ * HD_;
  for (int i = 0; i < 64; i++) {
    int t = t0 + i;
    float kv = 0.f, vv = 0.f;
    if (t < PRE_) {
      kv = kp[(size_t)t * HD_ + tid];
      vv = vp[(size_t)t * HD_ + tid];
    }
    Kf[((size_t)b * TPAD_ + t) * HD_ + tid] = f2bf(kv);
    vt[tid][i] = f2bf(vv);
  }
  __syncthreads();
#pragma unroll
  for (int p = 0; p < 4; p++) {
    int d = p * 64 + (tid >> 2);
    int c0 = (tid & 3) * 16;
    u16x8 v0, v1;
#pragma unroll
    for (int j = 0; j < 8; j++) { v0[j] = vt[d][c0 + j]; v1[j] = vt[d][c0 + 8 + j]; }
    size_t dst = ((size_t)(b * HD_ + d)) * TPAD_ + t0 + c0;
    *(u16x8*)(Vt + dst) = v0;
    *(u16x8*)(Vt + dst + 8) = v1;
  }
}

// ================================================================ QKV GEMM + inline-ada A + RoPE/scatter epilogue
// grid (80 strips, 2 m-halves), 512 thr. Strips: 0..63 Q (head=st>>3, pair base x=(st&7)*16, cols dd & dd+128),
// 64..71 K (paired), 72..79 V (plain 32 cols). A = bf16(h*rs*w2) computed on the fly.
__global__ __launch_bounds__(512) void qkvF_k(const float* __restrict__ hsrc, const float* __restrict__ ssB,
                                              const float* __restrict__ w2, const float* __restrict__ Wq,
                                              const float* __restrict__ Wk, const float* __restrict__ Wv,
                                              const int* __restrict__ offs,
                                              unsigned short* __restrict__ q_r, unsigned short* __restrict__ Kf,
                                              unsigned short* __restrict__ Vt) {
  const int st = blockIdx.x, mh = blockIdx.y;
  const int tid = threadIdx.x, wv = tid >> 6, l = tid & 63;
  const int lr = l & 15, kg = l >> 4, lk = kg << 2;
  const int m0blk = mh * 256, m0 = m0blk + wv * 32;

  const float* W;
  int ldw, wbase;
  bool paired;
  if (st < 64)      { W = Wq; ldw = 2048; wbase = (st >> 3) * 256 + (st & 7) * 16; paired = true; }
  else if (st < 72) { W = Wk; ldw = 256;  wbase = (st - 64) * 16; paired = true; }
  else              { W = Wv; ldw = 256;  wbase = (st - 72) * 32; paired = false; }

  __shared__ unsigned short Wt[2][32][LST_];
  __shared__ float rsL[256];
  __shared__ int offsL[8];
  const int pr = tid >> 3, c0 = (tid & 7) * 4;
  const int wcol = wbase + c0 + ((paired && c0 >= 16) ? 112 : 0);

  if (tid < 256) {
    int row = m0blk + tid;
    float rs = 0.f;
    if (row < MROWS_) {
      float ss = 0.f;
#pragma unroll
      for (int p = 0; p < 64; p++) ss += ssB[(size_t)p * 512 + row];
      rs = rsqrtf(ss * (1.f / 1024.f) + 1e-6f);
    }
    rsL[tid] = rs;
  } else if (tid < 264) {
    offsL[tid - 256] = offs[tid - 256];
  }

  f32x4 acc[2][2];
#pragma unroll
  for (int a = 0; a < 2; a++)
#pragma unroll
    for (int b = 0; b < 2; b++) acc[a][b] = (f32x4){0.f, 0.f, 0.f, 0.f};

  f32x4 pa0, pa1;
  auto LOADW = [&](int IT) {
    size_t kk = (size_t)IT * KSTEP_ + 2 * pr;
    pa0 = *(const f32x4*)(W + kk * ldw + wcol);
    pa1 = *(const f32x4*)(W + (kk + 1) * ldw + wcol);
  };
  auto STOREW = [&](int BUF) {
#pragma unroll
    for (int j = 0; j < 4; j++) {
      unsigned v = (unsigned)f2bf(pa0[j]) | ((unsigned)f2bf(pa1[j]) << 16);
      *(unsigned*)&Wt[BUF][c0 + j][2 * pr] = v;
    }
  };

  LOADW(0);
  STOREW(0);
  __syncthreads();

  int rowA[2];
  float rsv[2];
  const float* w2p[2];
#pragma unroll
  for (int mf = 0; mf < 2; mf++) {
    rowA[mf] = m0 + mf * 16 + lr;
    rsv[mf] = rsL[rowA[mf] - m0blk];
    int b = rowA[mf] / 50;
    if (b > 7) b = 7;
    w2p[mf] = w2 + (size_t)b * 1024;
  }

  for (int it = 0; it < 8; ++it) {
    if (it + 1 < 8) LOADW(it + 1);
    const int cur = it & 1, kb = it * KSTEP_;
#pragma unroll
    for (int s = 0; s < 4; s++) {
      s16x8 bfr[2];
#pragma unroll
      for (int nf = 0; nf < 2; nf++) {
        const unsigned short* wp = &Wt[cur][nf * 16 + lr][s * 32 + 2 * lk];
        s16x4 b0 = *(const s16x4*)wp;
        s16x4 b1 = *(const s16x4*)(wp + 4);
#pragma unroll
        for (int j = 0; j < 4; j++) { bfr[nf][j] = b0[j]; bfr[nf][4 + j] = b1[j]; }
      }
#pragma unroll
      for (int mf = 0; mf < 2; mf++) {
        const float* hp = hsrc + (size_t)rowA[mf] * 1024 + kb + s * 32 + 8 * kg;
        f32x4 h0 = *(const f32x4*)hp, h1 = *(const f32x4*)(hp + 4);
        const float* up = w2p[mf] + kb + s * 32 + 8 * kg;
        f32x4 u0 = *(const f32x4*)up, u1 = *(const f32x4*)(up + 4);
        s16x8 a;
#pragma unroll
        for (int j = 0; j < 4; j++) {
          a[j] = (short)f2bf(h0[j] * rsv[mf] * u0[j]);
          a[4 + j] = (short)f2bf(h1[j] * rsv[mf] * u1[j]);
        }
#pragma unroll
        for (int nf = 0; nf < 2; nf++)
          acc[mf][nf] = __builtin_amdgcn_mfma_f32_16x16x32_bf16(a, bfr[nf], acc[mf][nf], 0, 0, 0);
      }
    }
    if (it + 1 < 8) STOREW((it + 1) & 1);
    __syncthreads();
  }

  const float RK = -9.210340371976184f / 128.0f;
  if (st < 64) {  // Q: rope pair (dd, dd+128), write q_r
    const int h = st >> 3, x = (st & 7) * 16, dd = x + lr;
    const float inv = expf((float)dd * RK);
#pragma unroll
    for (int mf = 0; mf < 2; mf++)
#pragma unroll
      for (int r = 0; r < 4; r++) {
        int m = m0 + mf * 16 + lk + r;
        if (m >= MROWS_) continue;
        int b = m / 50, s = m - b * 50;
        float ang = (float)(offsL[b] + s) * inv;
        float cc = cosf(ang), sn = sinf(ang);
        float v1 = acc[mf][0][r], v2 = acc[mf][1][r];
        size_t base = ((size_t)(b * NH_ + h) * 64 + s) * HD_;
        q_r[base + dd] = f2bf(v1 * cc - v2 * sn);
        q_r[base + dd + 128] = f2bf(v2 * cc + v1 * sn);
      }
  } else if (st < 72) {  // K: rope pair, write Kf suffix rows
    const int x = (st - 64) * 16, dd = x + lr;
    const float inv = expf((float)dd * RK);
#pragma unroll
    for (int mf = 0; mf < 2; mf++)
#pragma unroll
      for (int r = 0; r < 4; r++) {
        int m = m0 + mf * 16 + lk + r;
        if (m >= MROWS_) continue;
        int b = m / 50, s = m - b * 50;
        float ang = (float)(offsL[b] + s) * inv;
        float cc = cosf(ang), sn = sinf(ang);
        float v1 = acc[mf][0][r], v2 = acc[mf][1][r];
        size_t base = ((size_t)b * TPAD_ + PRE_ + s) * HD_;
        Kf[base + dd] = f2bf(v1 * cc - v2 * sn);
        Kf[base + dd + 128] = f2bf(v2 * cc + v1 * sn);
      }
  } else {  // V: write Vt columns
    const int x = (st - 72) * 32;
#pragma unroll
    for (int mf = 0; mf < 2; mf++)
#pragma unroll
      for (int nf = 0; nf < 2; nf++)
#pragma unroll
        for (int r = 0; r < 4; r++) {
          int m = m0 + mf * 16 + lk + r;
          if (m >= MROWS_) continue;
          int b = m / 50, s = m - b * 50;
          int d = x + nf * 16 + lr;
          Vt[((size_t)(b * HD_ + d)) * TPAD_ + PRE_ + s] = f2bf(acc[mf][nf][r]);
        }
  }
}

// ================================================================ fused flash attention (validated round-5)
__global__ __launch_bounds__(256) void flashF_k(const unsigned short* __restrict__ qr,
                                                const unsigned short* __restrict__ Kf,
                                                const unsigned short* __restrict__ Vt,
                                                unsigned short* __restrict__ attb) {
  const int rg = blockIdx.x, h = blockIdx.y, b = blockIdx.z;
  const int bh = b * NH_ + h;
  const int tid = threadIdx.x, w = tid >> 6, l = tid & 63;
  const int lr = l & 15, kg = l >> 4;
  const int t0 = w * 256;

  __shared__ union {
    unsigned short P[4][16][264];
    struct { float O[4][16][256]; float ml[4][16][2]; } c;
  } sm;

  f32x4 sc[16];
#pragma unroll
  for (int nf = 0; nf < 16; nf++) sc[nf] = (f32x4){0.f, 0.f, 0.f, 0.f};
  const unsigned short* qbase = qr + ((size_t)bh * 64 + rg * 16 + lr) * HD_;
  const unsigned short* kbase = Kf + ((size_t)b * TPAD_ + t0 + lr) * HD_;
#pragma unroll
  for (int k0 = 0; k0 < HD_; k0 += 32) {
    s16x8 a = *(const s16x8*)(qbase + k0 + 8 * kg);
#pragma unroll
    for (int nf = 0; nf < 16; nf++) {
      s16x8 bv = *(const s16x8*)(kbase + (size_t)nf * 16 * HD_ + k0 + 8 * kg);
      sc[nf] = __builtin_amdgcn_mfma_f32_16x16x32_bf16(a, bv, sc[nf], 0, 0, 0);
    }
  }
  float mx[4] = {-3.0e38f, -3.0e38f, -3.0e38f, -3.0e38f};
#pragma unroll
  for (int nf = 0; nf < 16; nf++) {
    int t = t0 + nf * 16 + lr;
#pragma unroll
    for (int r = 0; r < 4; r++) {
      int row = rg * 16 + 4 * kg + r;
      float v = sc[nf][r] * 0.0625f;
      if (t >= PRE_ && (t - PRE_) > row) v = -1e9f;
      sc[nf][r] = v;
      mx[r] = fmaxf(mx[r], v);
    }
  }
#pragma unroll
  for (int o = 8; o > 0; o >>= 1)
#pragma unroll
    for (int r = 0; r < 4; r++) mx[r] = fmaxf(mx[r], __shfl_xor(mx[r], o));
  float ls[4] = {0.f, 0.f, 0.f, 0.f};
#pragma unroll
  for (int nf = 0; nf < 16; nf++)
#pragma unroll
    for (int r = 0; r < 4; r++) {
      float p = expf(sc[nf][r] - mx[r]);
      sc[nf][r] = p;
      ls[r] += p;
    }
#pragma unroll
  for (int o = 8; o > 0; o >>= 1)
#pragma unroll
    for (int r = 0; r < 4; r++) ls[r] += __shfl_xor(ls[r], o);
#pragma unroll
  for (int nf = 0; nf < 16; nf++)
#pragma unroll
    for (int r = 0; r < 4; r++) sm.P[w][4 * kg + r][nf * 16 + lr] = f2bf(sc[nf][r]);
  __syncthreads();
  f32x4 o4[16];
#pragma unroll
  for (int nf = 0; nf < 16; nf++) o4[nf] = (f32x4){0.f, 0.f, 0.f, 0.f};
  const unsigned short* vbase = Vt + ((size_t)(b * HD_ + lr)) * TPAD_ + t0;
#pragma unroll
  for (int ti = 0; ti < 256; ti += 32) {
    s16x8 a = *(const s16x8*)&sm.P[w][lr][ti + 8 * kg];
#pragma unroll
    for (int nf = 0; nf < 16; nf++) {
      s16x8 bv = *(const s16x8*)(vbase + (size_t)nf * 16 * TPAD_ + ti + 8 * kg);
      o4[nf] = __builtin_amdgcn_mfma_f32_16x16x32_bf16(a, bv, o4[nf], 0, 0, 0);
    }
  }
  __syncthreads();
#pragma unroll
  for (int nf = 0; nf < 16; nf++)
#pragma unroll
    for (int r = 0; r < 4; r++) sm.c.O[w][4 * kg + r][nf * 16 + lr] = o4[nf][r];
  if (lr == 0) {
#pragma unroll
    for (int r = 0; r < 4; r++) {
      sm.c.ml[w][4 * kg + r][0] = mx[r];
      sm.c.ml[w][4 * kg + r][1] = ls[r];
    }
  }
  __syncthreads();
#pragma unroll
  for (int row = 0; row < 16; row++) {
    int s = rg * 16 + row;
    if (s >= HOR_) break;
    float M = -3.0e38f;
#pragma unroll
    for (int z = 0; z < 4; z++) M = fmaxf(M, sm.c.ml[z][row][0]);
    float den = 0.f, o = 0.f;
#pragma unroll
    for (int z = 0; z < 4; z++) {
      float wz = expf(sm.c.ml[z][row][0] - M);
      den += wz * sm.c.ml[z][row][1];
      o += wz * sm.c.O[z][row][tid];
    }
    attb[((size_t)(b * HOR_ + s)) * 2048 + h * HD_ + tid] = f2bf(o / den);
  }
}

// ================================================================ projection GEMM (W_o / down) + gated residual + SS partials
// grid (64 strips of 16 cols, 4 m-quarters), 512 thr. Full-K. ssX[strip][row] = sum of 16 cols of h^2.
template <int NITER, int LDA>
__global__ __launch_bounds__(512) void projF_k(const unsigned short* __restrict__ A, const float* __restrict__ W,
                                               const float* __restrict__ hprev, const float* __restrict__ gatev,
                                               float* __restrict__ hout, float* __restrict__ ssX) {
  const int strip = blockIdx.x, mq = blockIdx.y;
  const int n0 = strip * 16;
  const int tid = threadIdx.x, wv = tid >> 6, l = tid & 63;
  const int lr = l & 15, kg = l >> 4, lk = kg << 2;
  const int m0 = mq * 128 + wv * 16;

  __shared__ unsigned short Wt[2][16][LST_];
  const bool act = tid < 256;
  const int pr = tid >> 2, c0 = (tid & 3) * 4;

  f32x4 acc = (f32x4){0.f, 0.f, 0.f, 0.f};
  f32x4 pa0, pa1;
  auto LOADW = [&](int IT) {
    if (act) {
      size_t kk = (size_t)IT * KSTEP_ + 2 * pr;
      pa0 = *(const f32x4*)(W + kk * 1024 + n0 + c0);
      pa1 = *(const f32x4*)(W + (kk + 1) * 1024 + n0 + c0);
    }
  };
  auto STOREW = [&](int BUF) {
    if (act) {
#pragma unroll
      for (int j = 0; j < 4; j++) {
        unsigned v = (unsigned)f2bf(pa0[j]) | ((unsigned)f2bf(pa1[j]) << 16);
        *(unsigned*)&Wt[BUF][c0 + j][2 * pr] = v;
      }
    }
  };

  LOADW(0);
  STOREW(0);
  __syncthreads();
  for (int it = 0; it < NITER; ++it) {
    if (it + 1 < NITER) LOADW(it + 1);
    const int cur = it & 1, kb = it * KSTEP_;
#pragma unroll
    for (int s = 0; s < 4; s++) {
      s16x8 bfr;
      {
        const unsigned short* wp = &Wt[cur][lr][s * 32 + 2 * lk];
        s16x4 b0 = *(const s16x4*)wp;
        s16x4 b1 = *(const s16x4*)(wp + 4);
#pragma unroll
        for (int j = 0; j < 4; j++) { bfr[j] = b0[j]; bfr[4 + j] = b1[j]; }
      }
      s16x8 a = *(const s16x8*)(A + (size_t)(m0 + lr) * LDA + kb + s * 32 + 8 * kg);
      acc = __builtin_amdgcn_mfma_f32_16x16x32_bf16(a, bfr, acc, 0, 0, 0);
    }
    if (it + 1 < NITER) STOREW((it + 1) & 1);
    __syncthreads();
  }

#pragma unroll
  for (int r = 0; r < 4; r++) {
    int row = m0 + lk + r, col = n0 + lr;
    float o = 0.f;
    if (row < MROWS_) {
      int b = row / 50;
      size_t idx = (size_t)row * 1024 + col;
      o = hprev[idx] + gatev[(size_t)b * 1024 + col] * acc[r];
      hout[idx] = o;
    }
    float p2 = o * o;
#pragma unroll
    for (int off = 1; off < 16; off <<= 1) p2 += __shfl_xor(p2, off);
    if (lr == 0) ssX[(size_t)strip * 512 + row] = p2;
  }
}

// ================================================================ upgate dual GEMM + inline-ada A -> t = gelu(g)*u
// grid (128 strips of 32, 2 m-halves), 512 thr.
__global__ __launch_bounds__(512) void upgF_k(const float* __restrict__ hsrc, const float* __restrict__ ssA,
                                              const float* __restrict__ w2, const float* __restrict__ Wg,
                                              const float* __restrict__ Wu, unsigned short* __restrict__ tb) {
  const int st = blockIdx.x, mh = blockIdx.y;
  const int n0 = st * 32;
  const int tid = threadIdx.x, wv = tid >> 6, l = tid & 63;
  const int lr = l & 15, kg = l >> 4, lk = kg << 2;
  const int m0blk = mh * 256, m0 = m0blk + wv * 32;

  __shared__ unsigned short Wt[2][64][LST_];
  __shared__ float rsL[256];
  const int pr = tid >> 3, c0 = (tid & 7) * 4;

  if (tid < 256) {
    int row = m0blk + tid;
    float rs = 0.f;
    if (row < MROWS_) {
      float ss = 0.f;
#pragma unroll
      for (int p = 0; p < 64; p++) ss += ssA[(size_t)p * 512 + row];
      rs = rsqrtf(ss * (1.f / 1024.f) + 1e-6f);
    }
    rsL[tid] = rs;
  }

  f32x4 acc[2][4];
#pragma unroll
  for (int a = 0; a < 2; a++)
#pragma unroll
    for (int b = 0; b < 4; b++) acc[a][b] = (f32x4){0.f, 0.f, 0.f, 0.f};

  f32x4 pa0, pa1, pb0, pb1;
  auto LOADW = [&](int IT) {
    size_t kk = (size_t)IT * KSTEP_ + 2 * pr;
    pa0 = *(const f32x4*)(Wg + kk * 4096 + n0 + c0);
    pa1 = *(const f32x4*)(Wg + (kk + 1) * 4096 + n0 + c0);
    pb0 = *(const f32x4*)(Wu + kk * 4096 + n0 + c0);
    pb1 = *(const f32x4*)(Wu + (kk + 1) * 4096 + n0 + c0);
  };
  auto STOREW = [&](int BUF) {
#pragma unroll
    for (int j = 0; j < 4; j++) {
      unsigned v = (unsigned)f2bf(pa0[j]) | ((unsigned)f2bf(pa1[j]) << 16);
      *(unsigned*)&Wt[BUF][c0 + j][2 * pr] = v;
      unsigned u = (unsigned)f2bf(pb0[j]) | ((unsigned)f2bf(pb1[j]) << 16);
      *(unsigned*)&Wt[BUF][32 + c0 + j][2 * pr] = u;
    }
  };

  LOADW(0);
  STOREW(0);
  __syncthreads();

  int rowA[2];
  float rsv[2];
  const float* w2p[2];
#pragma unroll
  for (int mf = 0; mf < 2; mf++) {
    rowA[mf] = m0 + mf * 16 + lr;
    rsv[mf] = rsL[rowA[mf] - m0blk];
    int b = rowA[mf] / 50;
    if (b > 7) b = 7;
    w2p[mf] = w2 + (size_t)b * 1024;
  }

  for (int it = 0; it < 8; ++it) {
    if (it + 1 < 8) LOADW(it + 1);
    const int cur = it & 1, kb = it * KSTEP_;
#pragma unroll
    for (int s = 0; s < 4; s++) {
      s16x8 bfr[4];
#pragma unroll
      for (int nf = 0; nf < 4; nf++) {
        const unsigned short* wp = &Wt[cur][nf * 16 + lr][s * 32 + 2 * lk];
        s16x4 b0 = *(const s16x4*)wp;
        s16x4 b1 = *(const s16x4*)(wp + 4);
#pragma unroll
        for (int j = 0; j < 4; j++) { bfr[nf][j] = b0[j]; bfr[nf][4 + j] = b1[j]; }
      }
#pragma unroll
      for (int mf = 0; mf < 2; mf++) {
        const float* hp = hsrc + (size_t)rowA[mf] * 1024 + kb + s * 32 + 8 * kg;
        f32x4 h0 = *(const f32x4*)hp, h1 = *(const f32x4*)(hp + 4);
        const float* up = w2p[mf] + kb + s * 32 + 8 * kg;
        f32x4 u0 = *(const f32x4*)up, u1 = *(const f32x4*)(up + 4);
        s16x8 a;
#pragma unroll
        for (int j = 0; j < 4; j++) {
          a[j] = (short)f2bf(h0[j] * rsv[mf] * u0[j]);
          a[4 + j] = (short)f2bf(h1[j] * rsv[mf] * u1[j]);
        }
#pragma unroll
        for (int nf = 0; nf < 4; nf++)
          acc[mf][nf] = __builtin_amdgcn_mfma_f32_16x16x32_bf16(a, bfr[nf], acc[mf][nf], 0, 0, 0);
      }
    }
    if (it + 1 < 8) STOREW((it + 1) & 1);
    __syncthreads();
  }

#pragma unroll
  for (int mf = 0; mf < 2; mf++)
#pragma unroll
    for (int nf = 0; nf < 2; nf++)
#pragma unroll
      for (int r = 0; r < 4; r++) {
        int row = m0 + mf * 16 + lk + r;
        if (row >= MROWS_) continue;
        int col = n0 + nf * 16 + lr;
        float g = acc[mf][nf][r];
        float u = acc[mf][nf + 2][r];
        g = 0.5f * g * (1.f + tanhf(0.7978845608028654f * (g + 0.044715f * g * g * g)));
        tb[(size_t)row * 4096 + col] = f2bf(g * u);
      }
}

// ---------------------------------------------------------------- out = ada(h) @ action_out_w + b (inline-ada)
__global__ __launch_bounds__(256) void fout2_k(const float* __restrict__ hbuf, const float* __restrict__ ssB,
                                               const float* __restrict__ fw2, const float* __restrict__ Wo,
                                               const float* __restrict__ bo, float* __restrict__ out) {
  int m = blockIdx.x, tid = threadIdx.x;
  __shared__ float ssL[64];
  __shared__ float rsS;
  if (tid < 64) ssL[tid] = ssB[(size_t)tid * 512 + m];
  __syncthreads();
  if (tid == 0) {
    float s = 0.f;
#pragma unroll
    for (int p = 0; p < 64; p++) s += ssL[p];
    rsS = rsqrtf(s * (1.f / 1024.f) + 1e-6f);
  }
  __syncthreads();
  int b = m / 50;
  const float* w2b = fw2 + (size_t)b * 1024;
  int n = tid & 31, kg2 = tid >> 5;
  float a = 0.f;
  for (int k = kg2 * 128; k < kg2 * 128 + 128; k++)
    a += hbuf[(size_t)m * 1024 + k] * w2b[k] * Wo[(size_t)k * AD_ + n];
  __shared__ float red[8][32];
  red[kg2][n] = a;
  __syncthreads();
  if (kg2 == 0) {
    float v = 0.f;
#pragma unroll
    for (int g = 0; g < 8; g++) v += red[g][n];
    out[(size_t)m * AD_ + n] = rsS * v + bo[n];
  }
}

// ================================================================ host
extern "C" void kernel_launch(void* const* d_in, const int* in_sizes, int n_in,
                              void* d_out, int out_size, void* d_ws, size_t ws_size,
                              hipStream_t stream) {
  const float* prefix_keys   = (const float*)d_in[0];
  const float* prefix_values = (const float*)d_in[1];
  const float* x_t           = (const float*)d_in[2];
  const float* timestep      = (const float*)d_in[3];
  const unsigned char* pad_mask = (const unsigned char*)d_in[4];
  const float* action_in_w   = (const float*)d_in[5];
  const float* action_in_b   = (const float*)d_in[6];
  const float* action_out_w  = (const float*)d_in[7];
  const float* action_out_b  = (const float*)d_in[8];
  const float* tmlp_in_w     = (const float*)d_in[9];
  const float* tmlp_in_b     = (const float*)d_in[10];
  const float* tmlp_out_w    = (const float*)d_in[11];
  const float* tmlp_out_b    = (const float*)d_in[12];
  const float* w_q    = (const float*)d_in[13];
  const float* w_k    = (const float*)d_in[14];
  const float* w_v    = (const float*)d_in[15];
  const float* w_o    = (const float*)d_in[16];
  const float* w_gate = (const float*)d_in[17];
  const float* w_up   = (const float*)d_in[18];
  const float* w_down = (const float*)d_in[19];
  const float* in_norm_w    = (const float*)d_in[20];
  const float* in_scale_w   = (const float*)d_in[21];
  const float* in_gate_w    = (const float*)d_in[22];
  const float* post_norm_w  = (const float*)d_in[23];
  const float* post_scale_w = (const float*)d_in[24];
  const float* post_gate_w  = (const float*)d_in[25];
  const float* fnorm_w       = (const float*)d_in[26];
  const float* fnorm_scale_w = (const float*)d_in[27];

  char* wsp = (char*)d_ws;
  auto alloc = [&](size_t bytes) { void* p = (void*)wsp; wsp += (bytes + 255) & ~(size_t)255; return p; };

  float* emb0   = (float*)alloc((size_t)8 * H_ * 4);
  float* emb1   = (float*)alloc((size_t)8 * H_ * 4);
  float* cond   = (float*)alloc((size_t)8 * H_ * 4);
  float* fscale = (float*)alloc((size_t)8 * H_ * 4);
  float* gates  = (float*)alloc((size_t)4 * L_ * 8 * H_ * 4);
  float* w2all  = (float*)alloc((size_t)37 * 8 * H_ * 4);
  int*   offs   = (int*)alloc(64);
  float* hbuf   = (float*)alloc((size_t)MPAD_ * H_ * 4);
  float* h1buf  = (float*)alloc((size_t)MPAD_ * H_ * 4);
  float* ssA    = (float*)alloc((size_t)64 * 512 * 4);
  float* ssB    = (float*)alloc((size_t)64 * 512 * 4);
  unsigned short* q_r    = (unsigned short*)alloc((size_t)B_ * NH_ * 64 * HD_ * 2);
  unsigned short* Kf_all = (unsigned short*)alloc((size_t)L_ * B_ * TPAD_ * HD_ * 2);
  unsigned short* Vt_all = (unsigned short*)alloc((size_t)L_ * B_ * HD_ * TPAD_ * 2);
  unsigned short* attb   = (unsigned short*)alloc((size_t)MPAD_ * 2048 * 2);
  unsigned short* t_buf  = (unsigned short*)alloc((size_t)MPAD_ * FF_ * 2);

  // attb pad rows never written by flashF: zero once
  hipMemsetAsync(attb + (size_t)MROWS_ * 2048, 0, (size_t)(MPAD_ - MROWS_) * 2048 * 2, stream);

  emb_k<<<8, 256, 0, stream>>>(timestep, emb0);
  gemm8_k<<<16, 256, 0, stream>>>(emb0, tmlp_in_w, tmlp_in_b, emb1, 1);
  gemm8_k<<<16, 256, 0, stream>>>(emb1, tmlp_out_w, tmlp_out_b, cond, 1);
  gemm8_k<<<16, 256, 0, stream>>>(cond, fnorm_scale_w, nullptr, fscale, 0);
  gates_k<<<dim3(16, L_, 4), 256, 0, stream>>>(cond, in_scale_w, in_gate_w, post_scale_w, post_gate_w, gates);
  w2p_k<<<dim3(37, 8), 256, 0, stream>>>(in_norm_w, post_norm_w, fnorm_w, gates, fscale, w2all);
  offs_k<<<1, 256, 0, stream>>>(pad_mask, offs);
  action_in_k<<<(MPAD_ * H_) / 256, 256, 0, stream>>>(x_t, action_in_w, action_in_b, hbuf);
  rowss0_k<<<MPAD_, 256, 0, stream>>>(hbuf, ssB);
  prefixAll_k<<<dim3(16, B_, L_), 256, 0, stream>>>(prefix_keys, prefix_values, Kf_all, Vt_all);

  for (int i = 0; i < L_; i++) {
    const float* wq_i = w_q + (size_t)i * H_ * 2048;
    const float* wk_i = w_k + (size_t)i * H_ * HD_;
    const float* wv_i = w_v + (size_t)i * H_ * HD_;
    const float* wo_i = w_o + (size_t)i * 2048 * H_;
    const float* wg_i = w_gate + (size_t)i * H_ * FF_;
    const float* wu_i = w_up + (size_t)i * H_ * FF_;
    const float* wd_i = w_down + (size_t)i * FF_ * H_;
    const float* g_in_gate   = gates + ((size_t)(1 * L_ + i) * 8) * H_;
    const float* g_post_gate = gates + ((size_t)(3 * L_ + i) * 8) * H_;
    const float* w2_in   = w2all + (size_t)i * 8 * H_;
    const float* w2_post = w2all + (size_t)(18 + i) * 8 * H_;
    unsigned short* Kf_l = Kf_all + (size_t)i * B_ * TPAD_ * HD_;
    unsigned short* Vt_l = Vt_all + (size_t)i * B_ * HD_ * TPAD_;

    qkvF_k<<<dim3(80, 2), 512, 0, stream>>>(hbuf, ssB, w2_in, wq_i, wk_i, wv_i, offs, q_r, Kf_l, Vt_l);
    flashF_k<<<dim3(4, NH_, B_), 256, 0, stream>>>(q_r, Kf_l, Vt_l, attb);
    projF_k<16, 2048><<<dim3(64, 4), 512, 0, stream>>>(attb, wo_i, hbuf, g_in_gate, h1buf, ssA);
    upgF_k<<<dim3(128, 2), 512, 0, stream>>>(h1buf, ssA, w2_post, wg_i, wu_i, t_buf);
    projF_k<32, 4096><<<dim3(64, 4), 512, 0, stream>>>(t_buf, wd_i, h1buf, g_post_gate, hbuf, ssB);
  }

  fout2_k<<<MROWS_, 256, 0, stream>>>(hbuf, ssB, w2all + (size_t)36 * 8 * H_, action_out_w, action_out_b,
                                      (float*)d_out);
}

// Round 9
// 4375.916 us; speedup vs baseline: 2.6187x; 1.1912x over previous
//
#include <hip/hip_runtime.h>

#define L_ 18
#define H_ 1024
#define NH_ 8
#define HD_ 256
#define FF_ 4096
#define HOR_ 50
#define PRE_ 968
#define B_ 8
#define AD_ 32
#define TPAD_ 1024
#define MROWS_ 400
#define MPAD_ 512
#define KSTEP_ 128
#define LST_ 132

typedef float f32x4 __attribute__((ext_vector_type(4)));
typedef short s16x4 __attribute__((ext_vector_type(4)));
typedef short s16x8 __attribute__((ext_vector_type(8)));
typedef unsigned short u16x8 __attribute__((ext_vector_type(8)));

__device__ __forceinline__ unsigned short f2bf(float f) {
  unsigned u = __float_as_uint(f);
  u += 0x7FFFu + ((u >> 16) & 1u);
  return (unsigned short)(u >> 16);
}
__device__ __forceinline__ float bf2f(unsigned short h) {
  return __uint_as_float(((unsigned)h) << 16);
}
__device__ __forceinline__ float wave_sum(float v) {
#pragma unroll
  for (int o = 32; o > 0; o >>= 1) v += __shfl_xor(v, o);
  return v;
}

// ---------------------------------------------------------------- time embedding
__global__ __launch_bounds__(256) void emb_k(const float* __restrict__ ts, float* __restrict__ emb) {
  int b = blockIdx.x, tid = threadIdx.x;
  float t = ts[b];
  for (int j = tid; j < 512; j += 256) {
    float ang = 1570.7963267948966f * expf((float)j * (-6.907755278982137f / 511.0f)) * t;
    emb[(size_t)b * H_ + j] = sinf(ang);
    emb[(size_t)b * H_ + 512 + j] = cosf(ang);
  }
}

// ---------------------------------------------------------------- [8,1024]@[1024,1024] (+bias,+silu)
__global__ __launch_bounds__(256) void gemm8_k(const float* __restrict__ A8, const float* __restrict__ W,
                                               const float* __restrict__ bias, float* __restrict__ out,
                                               int act) {
  __shared__ float a_s[8 * 1024];
  __shared__ float red[4][8][64];
  int tid = threadIdx.x;
  for (int i = tid; i < 8 * 1024; i += 256) a_s[i] = A8[i];
  __syncthreads();
  int nl = tid & 63, kg = tid >> 6;
  int n = blockIdx.x * 64 + nl;
  float acc[8];
#pragma unroll
  for (int m = 0; m < 8; m++) acc[m] = 0.f;
  for (int k = kg * 256; k < kg * 256 + 256; k++) {
    float wv = W[(size_t)k * 1024 + n];
#pragma unroll
    for (int m = 0; m < 8; m++) acc[m] += a_s[m * 1024 + k] * wv;
  }
#pragma unroll
  for (int m = 0; m < 8; m++) red[kg][m][nl] = acc[m];
  __syncthreads();
  if (kg == 0) {
#pragma unroll
    for (int m = 0; m < 8; m++) {
      float v = red[0][m][nl] + red[1][m][nl] + red[2][m][nl] + red[3][m][nl];
      if (bias) v += bias[n];
      if (act) v = v / (1.f + expf(-v));
      out[(size_t)m * 1024 + n] = v;
    }
  }
}

// ---------------------------------------------------------------- all 72 adaLN cond GEMMs in one grid
__global__ __launch_bounds__(256) void gates_k(const float* __restrict__ cond,
                                               const float* __restrict__ w0, const float* __restrict__ w1,
                                               const float* __restrict__ w2, const float* __restrict__ w3,
                                               float* __restrict__ gates) {
  __shared__ float a_s[8 * 1024];
  __shared__ float red[4][8][64];
  int tid = threadIdx.x;
  for (int i = tid; i < 8 * 1024; i += 256) a_s[i] = cond[i];
  __syncthreads();
  int z = blockIdx.z, layer = blockIdx.y;
  const float* W = (z == 0 ? w0 : z == 1 ? w1 : z == 2 ? w2 : w3) + (size_t)layer * H_ * H_;
  float* out = gates + ((size_t)(z * L_ + layer) * 8) * H_;
  int nl = tid & 63, kg = tid >> 6;
  int n = blockIdx.x * 64 + nl;
  float acc[8];
#pragma unroll
  for (int m = 0; m < 8; m++) acc[m] = 0.f;
  for (int k = kg * 256; k < kg * 256 + 256; k++) {
    float wv = W[(size_t)k * 1024 + n];
#pragma unroll
    for (int m = 0; m < 8; m++) acc[m] += a_s[m * 1024 + k] * wv;
  }
#pragma unroll
  for (int m = 0; m < 8; m++) red[kg][m][nl] = acc[m];
  __syncthreads();
  if (kg == 0) {
#pragma unroll
    for (int m = 0; m < 8; m++)
      out[(size_t)m * 1024 + n] = red[0][m][nl] + red[1][m][nl] + red[2][m][nl] + red[3][m][nl];
  }
}

// ---------------------------------------------------------------- pad-mask -> per-batch valid counts
__global__ void offs_k(const unsigned char* __restrict__ mask, int* __restrict__ offs) {
  __shared__ int cnt[8];
  __shared__ int mod4;
  int tid = threadIdx.x;
  if (tid < 8) cnt[tid] = 0;
  if (tid == 8) mod4 = 0;
  __syncthreads();
  for (int i = tid; i < B_ * PRE_; i += 256) {
    unsigned char v = mask[i];
    if (v) {
      atomicAdd(&cnt[i / PRE_], 1);
      if (i & 3) atomicAdd(&mod4, 1);
    }
  }
  __syncthreads();
  if (tid < 8) offs[tid] = (mod4 == 0) ? cnt[tid] * 4 : cnt[tid];
}

// ---------------------------------------------------------------- h = x_t @ action_in_w + b  (pad rows = 0)
__global__ __launch_bounds__(256) void action_in_k(const float* __restrict__ xt, const float* __restrict__ Wi,
                                                   const float* __restrict__ bi, float* __restrict__ h) {
  int idx = blockIdx.x * 256 + threadIdx.x;
  int m = idx >> 10, n = idx & 1023;
  float v = 0.f;
  if (m < MROWS_) {
    const float* xr = xt + (size_t)m * AD_;
#pragma unroll
    for (int k = 0; k < AD_; k++) v += xr[k] * Wi[(size_t)k * H_ + n];
    v += bi[n];
  }
  h[idx] = v;
}

// ---------------------------------------------------------------- AdaRMSNorm -> bf16 (pad rows = 0)
__global__ __launch_bounds__(256) void ada_k(const float* __restrict__ X, const float* __restrict__ nw,
                                             const float* __restrict__ sc, unsigned short* __restrict__ Y) {
  int m = blockIdx.x, tid = threadIdx.x;
  size_t base = (size_t)m * H_;
  if (m >= MROWS_) {
#pragma unroll
    for (int j = 0; j < 4; j++) Y[base + tid * 4 + j] = 0;
    return;
  }
  f32x4 x = *(const f32x4*)(X + base + tid * 4);
  float ss = x[0] * x[0] + x[1] * x[1] + x[2] * x[2] + x[3] * x[3];
  __shared__ float r4[4];
  float wsv = wave_sum(ss);
  if ((tid & 63) == 0) r4[tid >> 6] = wsv;
  __syncthreads();
  float rs = rsqrtf((r4[0] + r4[1] + r4[2] + r4[3]) * (1.f / 1024.f) + 1e-6f);
  int b = m / HOR_;
#pragma unroll
  for (int j = 0; j < 4; j++) {
    int n = tid * 4 + j;
    Y[base + n] = f2bf(x[j] * rs * (1.f + nw[n]) * (1.f + sc[(size_t)b * H_ + n]));
  }
}

// ---------------------------------------------------------------- all-layer prefix convert: K row-major, V transposed
__global__ __launch_bounds__(256) void prefixAll_k(const float* __restrict__ pk, const float* __restrict__ pv,
                                                   unsigned short* __restrict__ Kf_all,
                                                   unsigned short* __restrict__ Vt_all) {
  int b = blockIdx.y, t0 = blockIdx.x * 64, layer = blockIdx.z, tid = threadIdx.x;
  unsigned short* Kf = Kf_all + (size_t)layer * B_ * TPAD_ * HD_;
  unsigned short* Vt = Vt_all + (size_t)layer * B_ * HD_ * TPAD_;
  __shared__ unsigned short vt[256][72];
  const float* kp = pk + ((size_t)(b * L_ + layer)) * PRE_ * HD_;
  const float* vp = pv + ((size_t)(b * L_ + layer)) * PRE_ * HD_;
  for (int i = 0; i < 64; i++) {
    int t = t0 + i;
    float kv = 0.f, vv = 0.f;
    if (t < PRE_) {
      kv = kp[(size_t)t * HD_ + tid];
      vv = vp[(size_t)t * HD_ + tid];
    }
    Kf[((size_t)b * TPAD_ + t) * HD_ + tid] = f2bf(kv);  // suffix rows rewritten per layer by qkvF
    vt[tid][i] = f2bf(vv);
  }
  __syncthreads();
#pragma unroll
  for (int p = 0; p < 4; p++) {
    int d = p * 64 + (tid >> 2);
    int c0 = (tid & 3) * 16;
    u16x8 v0, v1;
#pragma unroll
    for (int j = 0; j < 8; j++) { v0[j] = vt[d][c0 + j]; v1[j] = vt[d][c0 + 8 + j]; }
    size_t dst = ((size_t)(b * HD_ + d)) * TPAD_ + t0 + c0;
    *(u16x8*)(Vt + dst) = v0;
    *(u16x8*)(Vt + dst + 8) = v1;
  }
}

// ================================================================ QKV GEMM (bf16 A) + RoPE/scatter epilogue
// grid (80 strips, 2 m-halves), 512 thr. Strips: 0..63 Q (head=st>>3, pair (dd, dd+128)),
// 64..71 K (paired), 72..79 V (plain 32 cols). Full-K (NITER=8). Epilogue validated in round 8.
__global__ __launch_bounds__(512) void qkvF_k(const unsigned short* __restrict__ A,
                                              const float* __restrict__ Wq, const float* __restrict__ Wk,
                                              const float* __restrict__ Wv, const int* __restrict__ offs,
                                              unsigned short* __restrict__ q_r, unsigned short* __restrict__ Kf,
                                              unsigned short* __restrict__ Vt) {
  const int st = blockIdx.x, mh = blockIdx.y;
  const int tid = threadIdx.x, wv = tid >> 6, l = tid & 63;
  const int lr = l & 15, kg = l >> 4, lk = kg << 2;
  const int m0 = mh * 256 + wv * 32;

  const float* W;
  int ldw, wbase;
  bool paired;
  if (st < 64)      { W = Wq; ldw = 2048; wbase = (st >> 3) * 256 + (st & 7) * 16; paired = true; }
  else if (st < 72) { W = Wk; ldw = 256;  wbase = (st - 64) * 16; paired = true; }
  else              { W = Wv; ldw = 256;  wbase = (st - 72) * 32; paired = false; }

  __shared__ unsigned short Wt[2][32][LST_];
  __shared__ int offsL[8];
  const int pr = tid >> 3, c0 = (tid & 7) * 4;
  const int wcol = wbase + c0 + ((paired && c0 >= 16) ? 112 : 0);

  if (tid < 8) offsL[tid] = offs[tid];

  f32x4 acc[2][2];
#pragma unroll
  for (int a = 0; a < 2; a++)
#pragma unroll
    for (int b = 0; b < 2; b++) acc[a][b] = (f32x4){0.f, 0.f, 0.f, 0.f};

  f32x4 pa0, pa1;
  auto LOADW = [&](int IT) {
    size_t kk = (size_t)IT * KSTEP_ + 2 * pr;
    pa0 = *(const f32x4*)(W + kk * ldw + wcol);
    pa1 = *(const f32x4*)(W + (kk + 1) * ldw + wcol);
  };
  auto STOREW = [&](int BUF) {
#pragma unroll
    for (int j = 0; j < 4; j++) {
      unsigned v = (unsigned)f2bf(pa0[j]) | ((unsigned)f2bf(pa1[j]) << 16);
      *(unsigned*)&Wt[BUF][c0 + j][2 * pr] = v;
    }
  };

  LOADW(0);
  STOREW(0);
  __syncthreads();

  for (int it = 0; it < 8; ++it) {
    if (it + 1 < 8) LOADW(it + 1);
    const int cur = it & 1, kb = it * KSTEP_;
#pragma unroll
    for (int s = 0; s < 4; s++) {
      s16x8 bfr[2];
#pragma unroll
      for (int nf = 0; nf < 2; nf++) {
        const unsigned short* wp = &Wt[cur][nf * 16 + lr][s * 32 + 2 * lk];
        s16x4 b0 = *(const s16x4*)wp;
        s16x4 b1 = *(const s16x4*)(wp + 4);
#pragma unroll
        for (int j = 0; j < 4; j++) { bfr[nf][j] = b0[j]; bfr[nf][4 + j] = b1[j]; }
      }
#pragma unroll
      for (int mf = 0; mf < 2; mf++) {
        s16x8 a = *(const s16x8*)(A + (size_t)(m0 + mf * 16 + lr) * H_ + kb + s * 32 + 8 * kg);
#pragma unroll
        for (int nf = 0; nf < 2; nf++)
          acc[mf][nf] = __builtin_amdgcn_mfma_f32_16x16x32_bf16(a, bfr[nf], acc[mf][nf], 0, 0, 0);
      }
    }
    if (it + 1 < 8) STOREW((it + 1) & 1);
    __syncthreads();
  }

  const float RK = -9.210340371976184f / 128.0f;
  if (st < 64) {  // Q: rope pair, write q_r
    const int h = st >> 3, x = (st & 7) * 16, dd = x + lr;
    const float inv = expf((float)dd * RK);
#pragma unroll
    for (int mf = 0; mf < 2; mf++)
#pragma unroll
      for (int r = 0; r < 4; r++) {
        int m = m0 + mf * 16 + lk + r;
        if (m >= MROWS_) continue;
        int b = m / HOR_, s = m - b * HOR_;
        float ang = (float)(offsL[b] + s) * inv;
        float cc = cosf(ang), sn = sinf(ang);
        float v1 = acc[mf][0][r], v2 = acc[mf][1][r];
        size_t base = ((size_t)(b * NH_ + h) * 64 + s) * HD_;
        q_r[base + dd] = f2bf(v1 * cc - v2 * sn);
        q_r[base + dd + 128] = f2bf(v2 * cc + v1 * sn);
      }
  } else if (st < 72) {  // K: rope pair, write Kf suffix rows
    const int x = (st - 64) * 16, dd = x + lr;
    const float inv = expf((float)dd * RK);
#pragma unroll
    for (int mf = 0; mf < 2; mf++)
#pragma unroll
      for (int r = 0; r < 4; r++) {
        int m = m0 + mf * 16 + lk + r;
        if (m >= MROWS_) continue;
        int b = m / HOR_, s = m - b * HOR_;
        float ang = (float)(offsL[b] + s) * inv;
        float cc = cosf(ang), sn = sinf(ang);
        float v1 = acc[mf][0][r], v2 = acc[mf][1][r];
        size_t base = ((size_t)b * TPAD_ + PRE_ + s) * HD_;
        Kf[base + dd] = f2bf(v1 * cc - v2 * sn);
        Kf[base + dd + 128] = f2bf(v2 * cc + v1 * sn);
      }
  } else {  // V: write Vt columns
    const int x = (st - 72) * 32;
#pragma unroll
    for (int mf = 0; mf < 2; mf++)
#pragma unroll
      for (int nf = 0; nf < 2; nf++)
#pragma unroll
        for (int r = 0; r < 4; r++) {
          int m = m0 + mf * 16 + lk + r;
          if (m >= MROWS_) continue;
          int b = m / HOR_, s = m - b * HOR_;
          int d = x + nf * 16 + lr;
          Vt[((size_t)(b * HD_ + d)) * TPAD_ + PRE_ + s] = f2bf(acc[mf][nf][r]);
        }
  }
}

// ================================================================ fused flash attention (validated round-5)
__global__ __launch_bounds__(256) void flashF_k(const unsigned short* __restrict__ qr,
                                                const unsigned short* __restrict__ Kf,
                                                const unsigned short* __restrict__ Vt,
                                                unsigned short* __restrict__ attb) {
  const int rg = blockIdx.x, h = blockIdx.y, b = blockIdx.z;
  const int bh = b * NH_ + h;
  const int tid = threadIdx.x, w = tid >> 6, l = tid & 63;
  const int lr = l & 15, kg = l >> 4;
  const int t0 = w * 256;

  __shared__ union {
    unsigned short P[4][16][264];
    struct { float O[4][16][256]; float ml[4][16][2]; } c;
  } sm;

  f32x4 sc[16];
#pragma unroll
  for (int nf = 0; nf < 16; nf++) sc[nf] = (f32x4){0.f, 0.f, 0.f, 0.f};
  const unsigned short* qbase = qr + ((size_t)bh * 64 + rg * 16 + lr) * HD_;
  const unsigned short* kbase = Kf + ((size_t)b * TPAD_ + t0 + lr) * HD_;
#pragma unroll
  for (int k0 = 0; k0 < HD_; k0 += 32) {
    s16x8 a = *(const s16x8*)(qbase + k0 + 8 * kg);
#pragma unroll
    for (int nf = 0; nf < 16; nf++) {
      s16x8 bv = *(const s16x8*)(kbase + (size_t)nf * 16 * HD_ + k0 + 8 * kg);
      sc[nf] = __builtin_amdgcn_mfma_f32_16x16x32_bf16(a, bv, sc[nf], 0, 0, 0);
    }
  }
  float mx[4] = {-3.0e38f, -3.0e38f, -3.0e38f, -3.0e38f};
#pragma unroll
  for (int nf = 0; nf < 16; nf++) {
    int t = t0 + nf * 16 + lr;
#pragma unroll
    for (int r = 0; r < 4; r++) {
      int row = rg * 16 + 4 * kg + r;
      float v = sc[nf][r] * 0.0625f;
      if (t >= PRE_ && (t - PRE_) > row) v = -1e9f;
      sc[nf][r] = v;
      mx[r] = fmaxf(mx[r], v);
    }
  }
#pragma unroll
  for (int o = 8; o > 0; o >>= 1)
#pragma unroll
    for (int r = 0; r < 4; r++) mx[r] = fmaxf(mx[r], __shfl_xor(mx[r], o));
  float ls[4] = {0.f, 0.f, 0.f, 0.f};
#pragma unroll
  for (int nf = 0; nf < 16; nf++)
#pragma unroll
    for (int r = 0; r < 4; r++) {
      float p = expf(sc[nf][r] - mx[r]);
      sc[nf][r] = p;
      ls[r] += p;
    }
#pragma unroll
  for (int o = 8; o > 0; o >>= 1)
#pragma unroll
    for (int r = 0; r < 4; r++) ls[r] += __shfl_xor(ls[r], o);
#pragma unroll
  for (int nf = 0; nf < 16; nf++)
#pragma unroll
    for (int r = 0; r < 4; r++) sm.P[w][4 * kg + r][nf * 16 + lr] = f2bf(sc[nf][r]);
  __syncthreads();
  f32x4 o4[16];
#pragma unroll
  for (int nf = 0; nf < 16; nf++) o4[nf] = (f32x4){0.f, 0.f, 0.f, 0.f};
  const unsigned short* vbase = Vt + ((size_t)(b * HD_ + lr)) * TPAD_ + t0;
#pragma unroll
  for (int ti = 0; ti < 256; ti += 32) {
    s16x8 a = *(const s16x8*)&sm.P[w][lr][ti + 8 * kg];
#pragma unroll
    for (int nf = 0; nf < 16; nf++) {
      s16x8 bv = *(const s16x8*)(vbase + (size_t)nf * 16 * TPAD_ + ti + 8 * kg);
      o4[nf] = __builtin_amdgcn_mfma_f32_16x16x32_bf16(a, bv, o4[nf], 0, 0, 0);
    }
  }
  __syncthreads();
#pragma unroll
  for (int nf = 0; nf < 16; nf++)
#pragma unroll
    for (int r = 0; r < 4; r++) sm.c.O[w][4 * kg + r][nf * 16 + lr] = o4[nf][r];
  if (lr == 0) {
#pragma unroll
    for (int r = 0; r < 4; r++) {
      sm.c.ml[w][4 * kg + r][0] = mx[r];
      sm.c.ml[w][4 * kg + r][1] = ls[r];
    }
  }
  __syncthreads();
#pragma unroll
  for (int row = 0; row < 16; row++) {
    int s = rg * 16 + row;
    if (s >= HOR_) break;
    float M = -3.0e38f;
#pragma unroll
    for (int z = 0; z < 4; z++) M = fmaxf(M, sm.c.ml[z][row][0]);
    float den = 0.f, o = 0.f;
#pragma unroll
    for (int z = 0; z < 4; z++) {
      float wz = expf(sm.c.ml[z][row][0] - M);
      den += wz * sm.c.ml[z][row][1];
      o += wz * sm.c.O[z][row][tid];
    }
    attb[((size_t)(b * HOR_ + s)) * 2048 + h * HD_ + tid] = f2bf(o / den);
  }
}

// ================================================================ projection GEMM (W_o / down) + gated residual
// grid (64 strips of 16 cols, 4 m-quarters), 512 thr. Full-K deep pipeline.
template <int NITER, int LDA>
__global__ __launch_bounds__(512) void projF_k(const unsigned short* __restrict__ A, const float* __restrict__ W,
                                               const float* __restrict__ hprev, const float* __restrict__ gatev,
                                               float* __restrict__ hout) {
  const int strip = blockIdx.x, mq = blockIdx.y;
  const int n0 = strip * 16;
  const int tid = threadIdx.x, wv = tid >> 6, l = tid & 63;
  const int lr = l & 15, kg = l >> 4, lk = kg << 2;
  const int m0 = mq * 128 + wv * 16;

  __shared__ unsigned short Wt[2][16][LST_];
  const bool act = tid < 256;
  const int pr = tid >> 2, c0 = (tid & 3) * 4;

  f32x4 acc = (f32x4){0.f, 0.f, 0.f, 0.f};
  f32x4 pa0, pa1;
  auto LOADW = [&](int IT) {
    if (act) {
      size_t kk = (size_t)IT * KSTEP_ + 2 * pr;
      pa0 = *(const f32x4*)(W + kk * 1024 + n0 + c0);
      pa1 = *(const f32x4*)(W + (kk + 1) * 1024 + n0 + c0);
    }
  };
  auto STOREW = [&](int BUF) {
    if (act) {
#pragma unroll
      for (int j = 0; j < 4; j++) {
        unsigned v = (unsigned)f2bf(pa0[j]) | ((unsigned)f2bf(pa1[j]) << 16);
        *(unsigned*)&Wt[BUF][c0 + j][2 * pr] = v;
      }
    }
  };

  LOADW(0);
  STOREW(0);
  __syncthreads();
  for (int it = 0; it < NITER; ++it) {
    if (it + 1 < NITER) LOADW(it + 1);
    const int cur = it & 1, kb = it * KSTEP_;
#pragma unroll
    for (int s = 0; s < 4; s++) {
      s16x8 bfr;
      {
        const unsigned short* wp = &Wt[cur][lr][s * 32 + 2 * lk];
        s16x4 b0 = *(const s16x4*)wp;
        s16x4 b1 = *(const s16x4*)(wp + 4);
#pragma unroll
        for (int j = 0; j < 4; j++) { bfr[j] = b0[j]; bfr[4 + j] = b1[j]; }
      }
      s16x8 a = *(const s16x8*)(A + (size_t)(m0 + lr) * LDA + kb + s * 32 + 8 * kg);
      acc = __builtin_amdgcn_mfma_f32_16x16x32_bf16(a, bfr, acc, 0, 0, 0);
    }
    if (it + 1 < NITER) STOREW((it + 1) & 1);
    __syncthreads();
  }

#pragma unroll
  for (int r = 0; r < 4; r++) {
    int row = m0 + lk + r, col = n0 + lr;
    if (row < MROWS_) {
      int b = row / HOR_;
      size_t idx = (size_t)row * 1024 + col;
      hout[idx] = hprev[idx] + gatev[(size_t)b * 1024 + col] * acc[r];
    }
  }
}

// ================================================================ upgate dual GEMM -> t = gelu(g)*u (round-5)
// grid (128 strips of 32, 2 m-halves), 512 thr, full-K NITER=8.
__global__ __launch_bounds__(512) void upg_k(const unsigned short* __restrict__ A, const float* __restrict__ Wg,
                                             const float* __restrict__ Wu, unsigned short* __restrict__ tb) {
  const int st = blockIdx.x, mh = blockIdx.y;
  const int n0 = st * 32;
  const int tid = threadIdx.x, wv = tid >> 6, l = tid & 63;
  const int lr = l & 15, kg = l >> 4, lk = kg << 2;
  const int m0 = mh * 256 + wv * 32;

  __shared__ unsigned short Wt[2][64][LST_];
  const int pr = tid >> 3, c0 = (tid & 7) * 4;

  f32x4 acc[2][4];
#pragma unroll
  for (int a = 0; a < 2; a++)
#pragma unroll
    for (int b = 0; b < 4; b++) acc[a][b] = (f32x4){0.f, 0.f, 0.f, 0.f};

  f32x4 pa0, pa1, pb0, pb1;
  auto LOADW = [&](int IT) {
    size_t kk = (size_t)IT * KSTEP_ + 2 * pr;
    pa0 = *(const f32x4*)(Wg + kk * 4096 + n0 + c0);
    pa1 = *(const f32x4*)(Wg + (kk + 1) * 4096 + n0 + c0);
    pb0 = *(const f32x4*)(Wu + kk * 4096 + n0 + c0);
    pb1 = *(const f32x4*)(Wu + (kk + 1) * 4096 + n0 + c0);
  };
  auto STOREW = [&](int BUF) {
#pragma unroll
    for (int j = 0; j < 4; j++) {
      unsigned v = (unsigned)f2bf(pa0[j]) | ((unsigned)f2bf(pa1[j]) << 16);
      *(unsigned*)&Wt[BUF][c0 + j][2 * pr] = v;
      unsigned u = (unsigned)f2bf(pb0[j]) | ((unsigned)f2bf(pb1[j]) << 16);
      *(unsigned*)&Wt[BUF][32 + c0 + j][2 * pr] = u;
    }
  };

  LOADW(0);
  STOREW(0);
  __syncthreads();

  for (int it = 0; it < 8; ++it) {
    if (it + 1 < 8) LOADW(it + 1);
    const int cur = it & 1, kb = it * KSTEP_;
#pragma unroll
    for (int s = 0; s < 4; s++) {
      s16x8 bfr[4];
#pragma unroll
      for (int nf = 0; nf < 4; nf++) {
        const unsigned short* wp = &Wt[cur][nf * 16 + lr][s * 32 + 2 * lk];
        s16x4 b0 = *(const s16x4*)wp;
        s16x4 b1 = *(const s16x4*)(wp + 4);
#pragma unroll
        for (int j = 0; j < 4; j++) { bfr[nf][j] = b0[j]; bfr[nf][4 + j] = b1[j]; }
      }
#pragma unroll
      for (int mf = 0; mf < 2; mf++) {
        s16x8 a = *(const s16x8*)(A + (size_t)(m0 + mf * 16 + lr) * H_ + kb + s * 32 + 8 * kg);
#pragma unroll
        for (int nf = 0; nf < 4; nf++)
          acc[mf][nf] = __builtin_amdgcn_mfma_f32_16x16x32_bf16(a, bfr[nf], acc[mf][nf], 0, 0, 0);
      }
    }
    if (it + 1 < 8) STOREW((it + 1) & 1);
    __syncthreads();
  }

#pragma unroll
  for (int mf = 0; mf < 2; mf++)
#pragma unroll
    for (int nf = 0; nf < 2; nf++)
#pragma unroll
      for (int r = 0; r < 4; r++) {
        int row = m0 + mf * 16 + lk + r;
        if (row >= MROWS_) continue;
        int col = n0 + nf * 16 + lr;
        float g = acc[mf][nf][r];
        float u = acc[mf][nf + 2][r];
        g = 0.5f * g * (1.f + tanhf(0.7978845608028654f * (g + 0.044715f * g * g * g)));
        tb[(size_t)row * 4096 + col] = f2bf(g * u);
      }
}

// ---------------------------------------------------------------- out = normedF @ action_out_w + b
__global__ __launch_bounds__(256) void fout_k(const unsigned short* __restrict__ nf, const float* __restrict__ Wo,
                                              const float* __restrict__ bo, float* __restrict__ out) {
  int m = blockIdx.x, tid = threadIdx.x;
  int n = tid & 31, kg = tid >> 5;
  float acc = 0.f;
  for (int k = kg * 128; k < kg * 128 + 128; k++)
    acc += bf2f(nf[(size_t)m * H_ + k]) * Wo[(size_t)k * AD_ + n];
  __shared__ float red[8][32];
  red[kg][n] = acc;
  __syncthreads();
  if (kg == 0) {
    float v = 0.f;
#pragma unroll
    for (int g = 0; g < 8; g++) v += red[g][n];
    out[(size_t)m * AD_ + n] = v + bo[n];
  }
}

// ================================================================ host
extern "C" void kernel_launch(void* const* d_in, const int* in_sizes, int n_in,
                              void* d_out, int out_size, void* d_ws, size_t ws_size,
                              hipStream_t stream) {
  const float* prefix_keys   = (const float*)d_in[0];
  const float* prefix_values = (const float*)d_in[1];
  const float* x_t           = (const float*)d_in[2];
  const float* timestep      = (const float*)d_in[3];
  const unsigned char* pad_mask = (const unsigned char*)d_in[4];
  const float* action_in_w   = (const float*)d_in[5];
  const float* action_in_b   = (const float*)d_in[6];
  const float* action_out_w  = (const float*)d_in[7];
  const float* action_out_b  = (const float*)d_in[8];
  const float* tmlp_in_w     = (const float*)d_in[9];
  const float* tmlp_in_b     = (const float*)d_in[10];
  const float* tmlp_out_w    = (const float*)d_in[11];
  const float* tmlp_out_b    = (const float*)d_in[12];
  const float* w_q    = (const float*)d_in[13];
  const float* w_k    = (const float*)d_in[14];
  const float* w_v    = (const float*)d_in[15];
  const float* w_o    = (const float*)d_in[16];
  const float* w_gate = (const float*)d_in[17];
  const float* w_up   = (const float*)d_in[18];
  const float* w_down = (const float*)d_in[19];
  const float* in_norm_w    = (const float*)d_in[20];
  const float* in_scale_w   = (const float*)d_in[21];
  const float* in_gate_w    = (const float*)d_in[22];
  const float* post_norm_w  = (const float*)d_in[23];
  const float* post_scale_w = (const float*)d_in[24];
  const float* post_gate_w  = (const float*)d_in[25];
  const float* fnorm_w       = (const float*)d_in[26];
  const float* fnorm_scale_w = (const float*)d_in[27];

  char* wsp = (char*)d_ws;
  auto alloc = [&](size_t bytes) { void* p = (void*)wsp; wsp += (bytes + 255) & ~(size_t)255; return p; };

  float* emb0   = (float*)alloc((size_t)8 * H_ * 4);
  float* emb1   = (float*)alloc((size_t)8 * H_ * 4);
  float* cond   = (float*)alloc((size_t)8 * H_ * 4);
  float* fscale = (float*)alloc((size_t)8 * H_ * 4);
  float* gates  = (float*)alloc((size_t)4 * L_ * 8 * H_ * 4);
  int*   offs   = (int*)alloc(64);
  float* hbuf   = (float*)alloc((size_t)MPAD_ * H_ * 4);
  float* h1buf  = (float*)alloc((size_t)MPAD_ * H_ * 4);
  unsigned short* normed  = (unsigned short*)alloc((size_t)MPAD_ * H_ * 2);
  unsigned short* normed2 = (unsigned short*)alloc((size_t)MPAD_ * H_ * 2);
  unsigned short* q_r     = (unsigned short*)alloc((size_t)B_ * NH_ * 64 * HD_ * 2);
  unsigned short* Kf_all  = (unsigned short*)alloc((size_t)L_ * B_ * TPAD_ * HD_ * 2);
  unsigned short* Vt_all  = (unsigned short*)alloc((size_t)L_ * B_ * HD_ * TPAD_ * 2);
  unsigned short* attb    = (unsigned short*)alloc((size_t)MPAD_ * 2048 * 2);
  unsigned short* t_buf   = (unsigned short*)alloc((size_t)MPAD_ * FF_ * 2);

  // attb pad rows never written by flashF: zero once (stays zero all layers)
  hipMemsetAsync(attb + (size_t)MROWS_ * 2048, 0, (size_t)(MPAD_ - MROWS_) * 2048 * 2, stream);

  emb_k<<<8, 256, 0, stream>>>(timestep, emb0);
  gemm8_k<<<16, 256, 0, stream>>>(emb0, tmlp_in_w, tmlp_in_b, emb1, 1);
  gemm8_k<<<16, 256, 0, stream>>>(emb1, tmlp_out_w, tmlp_out_b, cond, 1);
  gemm8_k<<<16, 256, 0, stream>>>(cond, fnorm_scale_w, nullptr, fscale, 0);
  gates_k<<<dim3(16, L_, 4), 256, 0, stream>>>(cond, in_scale_w, in_gate_w, post_scale_w, post_gate_w, gates);
  offs_k<<<1, 256, 0, stream>>>(pad_mask, offs);
  action_in_k<<<(MPAD_ * H_) / 256, 256, 0, stream>>>(x_t, action_in_w, action_in_b, hbuf);
  prefixAll_k<<<dim3(16, B_, L_), 256, 0, stream>>>(prefix_keys, prefix_values, Kf_all, Vt_all);
  ada_k<<<MPAD_, 256, 0, stream>>>(hbuf, in_norm_w, gates, normed);  // layer-0 in_scale = gates z=0,l=0

  for (int i = 0; i < L_; i++) {
    const float* wq_i = w_q + (size_t)i * H_ * 2048;
    const float* wk_i = w_k + (size_t)i * H_ * HD_;
    const float* wv_i = w_v + (size_t)i * H_ * HD_;
    const float* wo_i = w_o + (size_t)i * 2048 * H_;
    const float* wg_i = w_gate + (size_t)i * H_ * FF_;
    const float* wu_i = w_up + (size_t)i * H_ * FF_;
    const float* wd_i = w_down + (size_t)i * FF_ * H_;
    const float* g_in_gate    = gates + ((size_t)(1 * L_ + i) * 8) * H_;
    const float* g_post_scale = gates + ((size_t)(2 * L_ + i) * 8) * H_;
    const float* g_post_gate  = gates + ((size_t)(3 * L_ + i) * 8) * H_;
    unsigned short* Kf_l = Kf_all + (size_t)i * B_ * TPAD_ * HD_;
    unsigned short* Vt_l = Vt_all + (size_t)i * B_ * HD_ * TPAD_;

    qkvF_k<<<dim3(80, 2), 512, 0, stream>>>(normed, wq_i, wk_i, wv_i, offs, q_r, Kf_l, Vt_l);
    flashF_k<<<dim3(4, NH_, B_), 256, 0, stream>>>(q_r, Kf_l, Vt_l, attb);
    projF_k<16, 2048><<<dim3(64, 4), 512, 0, stream>>>(attb, wo_i, hbuf, g_in_gate, h1buf);
    ada_k<<<MPAD_, 256, 0, stream>>>(h1buf, post_norm_w + (size_t)i * H_, g_post_scale, normed2);
    upg_k<<<dim3(128, 2), 512, 0, stream>>>(normed2, wg_i, wu_i, t_buf);
    projF_k<32, 4096><<<dim3(64, 4), 512, 0, stream>>>(t_buf, wd_i, h1buf, g_post_gate, hbuf);
    const float* nw_next = (i + 1 < L_) ? in_norm_w + (size_t)(i + 1) * H_ : fnorm_w;
    const float* sc_next = (i + 1 < L_) ? gates + ((size_t)(i + 1) * 8) * H_ : fscale;
    ada_k<<<MPAD_, 256, 0, stream>>>(hbuf, nw_next, sc_next, normed);
  }

  fout_k<<<MROWS_, 256, 0, stream>>>(normed, action_out_w, action_out_b, (float*)d_out);
}

// Round 10
// 3782.655 us; speedup vs baseline: 3.0294x; 1.1568x over previous
//
#include <hip/hip_runtime.h>

#define L_ 18
#define H_ 1024
#define NH_ 8
#define HD_ 256
#define FF_ 4096
#define HOR_ 50
#define PRE_ 968
#define B_ 8
#define AD_ 32
#define TPAD_ 1024
#define MROWS_ 400
#define MPAD_ 512
#define KSTEP_ 128
#define LST_ 132

typedef float f32x4 __attribute__((ext_vector_type(4)));
typedef short s16x4 __attribute__((ext_vector_type(4)));
typedef short s16x8 __attribute__((ext_vector_type(8)));
typedef unsigned short u16x8 __attribute__((ext_vector_type(8)));

__device__ __forceinline__ unsigned short f2bf(float f) {
  unsigned u = __float_as_uint(f);
  u += 0x7FFFu + ((u >> 16) & 1u);
  return (unsigned short)(u >> 16);
}
__device__ __forceinline__ float bf2f(unsigned short h) {
  return __uint_as_float(((unsigned)h) << 16);
}
__device__ __forceinline__ float wave_sum(float v) {
#pragma unroll
  for (int o = 32; o > 0; o >>= 1) v += __shfl_xor(v, o);
  return v;
}

// ---------------------------------------------------------------- time embedding
__global__ __launch_bounds__(256) void emb_k(const float* __restrict__ ts, float* __restrict__ emb) {
  int b = blockIdx.x, tid = threadIdx.x;
  float t = ts[b];
  for (int j = tid; j < 512; j += 256) {
    float ang = 1570.7963267948966f * expf((float)j * (-6.907755278982137f / 511.0f)) * t;
    emb[(size_t)b * H_ + j] = sinf(ang);
    emb[(size_t)b * H_ + 512 + j] = cosf(ang);
  }
}

// ---------------------------------------------------------------- [8,1024]@[1024,1024] (+bias,+silu)
__global__ __launch_bounds__(256) void gemm8_k(const float* __restrict__ A8, const float* __restrict__ W,
                                               const float* __restrict__ bias, float* __restrict__ out,
                                               int act) {
  __shared__ float a_s[8 * 1024];
  __shared__ float red[4][8][64];
  int tid = threadIdx.x;
  for (int i = tid; i < 8 * 1024; i += 256) a_s[i] = A8[i];
  __syncthreads();
  int nl = tid & 63, kg = tid >> 6;
  int n = blockIdx.x * 64 + nl;
  float acc[8];
#pragma unroll
  for (int m = 0; m < 8; m++) acc[m] = 0.f;
  for (int k = kg * 256; k < kg * 256 + 256; k++) {
    float wv = W[(size_t)k * 1024 + n];
#pragma unroll
    for (int m = 0; m < 8; m++) acc[m] += a_s[m * 1024 + k] * wv;
  }
#pragma unroll
  for (int m = 0; m < 8; m++) red[kg][m][nl] = acc[m];
  __syncthreads();
  if (kg == 0) {
#pragma unroll
    for (int m = 0; m < 8; m++) {
      float v = red[0][m][nl] + red[1][m][nl] + red[2][m][nl] + red[3][m][nl];
      if (bias) v += bias[n];
      if (act) v = v / (1.f + expf(-v));
      out[(size_t)m * 1024 + n] = v;
    }
  }
}

// ---------------------------------------------------------------- all 72 adaLN cond GEMMs in one grid
__global__ __launch_bounds__(256) void gates_k(const float* __restrict__ cond,
                                               const float* __restrict__ w0, const float* __restrict__ w1,
                                               const float* __restrict__ w2, const float* __restrict__ w3,
                                               float* __restrict__ gates) {
  __shared__ float a_s[8 * 1024];
  __shared__ float red[4][8][64];
  int tid = threadIdx.x;
  for (int i = tid; i < 8 * 1024; i += 256) a_s[i] = cond[i];
  __syncthreads();
  int z = blockIdx.z, layer = blockIdx.y;
  const float* W = (z == 0 ? w0 : z == 1 ? w1 : z == 2 ? w2 : w3) + (size_t)layer * H_ * H_;
  float* out = gates + ((size_t)(z * L_ + layer) * 8) * H_;
  int nl = tid & 63, kg = tid >> 6;
  int n = blockIdx.x * 64 + nl;
  float acc[8];
#pragma unroll
  for (int m = 0; m < 8; m++) acc[m] = 0.f;
  for (int k = kg * 256; k < kg * 256 + 256; k++) {
    float wv = W[(size_t)k * 1024 + n];
#pragma unroll
    for (int m = 0; m < 8; m++) acc[m] += a_s[m * 1024 + k] * wv;
  }
#pragma unroll
  for (int m = 0; m < 8; m++) red[kg][m][nl] = acc[m];
  __syncthreads();
  if (kg == 0) {
#pragma unroll
    for (int m = 0; m < 8; m++)
      out[(size_t)m * 1024 + n] = red[0][m][nl] + red[1][m][nl] + red[2][m][nl] + red[3][m][nl];
  }
}

// ---------------------------------------------------------------- pad-mask -> per-batch valid counts
__global__ void offs_k(const unsigned char* __restrict__ mask, int* __restrict__ offs) {
  __shared__ int cnt[8];
  __shared__ int mod4;
  int tid = threadIdx.x;
  if (tid < 8) cnt[tid] = 0;
  if (tid == 8) mod4 = 0;
  __syncthreads();
  for (int i = tid; i < B_ * PRE_; i += 256) {
    unsigned char v = mask[i];
    if (v) {
      atomicAdd(&cnt[i / PRE_], 1);
      if (i & 3) atomicAdd(&mod4, 1);
    }
  }
  __syncthreads();
  if (tid < 8) offs[tid] = (mod4 == 0) ? cnt[tid] * 4 : cnt[tid];
}

// ---------------------------------------------------------------- h = x_t @ action_in_w + b  (pad rows = 0)
__global__ __launch_bounds__(256) void action_in_k(const float* __restrict__ xt, const float* __restrict__ Wi,
                                                   const float* __restrict__ bi, float* __restrict__ h) {
  int idx = blockIdx.x * 256 + threadIdx.x;
  int m = idx >> 10, n = idx & 1023;
  float v = 0.f;
  if (m < MROWS_) {
    const float* xr = xt + (size_t)m * AD_;
#pragma unroll
    for (int k = 0; k < AD_; k++) v += xr[k] * Wi[(size_t)k * H_ + n];
    v += bi[n];
  }
  h[idx] = v;
}

// ---------------------------------------------------------------- AdaRMSNorm -> bf16 (pad rows = 0), layer-0 only
__global__ __launch_bounds__(256) void ada_k(const float* __restrict__ X, const float* __restrict__ nw,
                                             const float* __restrict__ sc, unsigned short* __restrict__ Y) {
  int m = blockIdx.x, tid = threadIdx.x;
  size_t base = (size_t)m * H_;
  if (m >= MROWS_) {
#pragma unroll
    for (int j = 0; j < 4; j++) Y[base + tid * 4 + j] = 0;
    return;
  }
  f32x4 x = *(const f32x4*)(X + base + tid * 4);
  float ss = x[0] * x[0] + x[1] * x[1] + x[2] * x[2] + x[3] * x[3];
  __shared__ float r4[4];
  float wsv = wave_sum(ss);
  if ((tid & 63) == 0) r4[tid >> 6] = wsv;
  __syncthreads();
  float rs = rsqrtf((r4[0] + r4[1] + r4[2] + r4[3]) * (1.f / 1024.f) + 1e-6f);
  int b = m / HOR_;
#pragma unroll
  for (int j = 0; j < 4; j++) {
    int n = tid * 4 + j;
    Y[base + n] = f2bf(x[j] * rs * (1.f + nw[n]) * (1.f + sc[(size_t)b * H_ + n]));
  }
}

// ---------------------------------------------------------------- all-layer prefix convert: K row-major, V transposed
__global__ __launch_bounds__(256) void prefixAll_k(const float* __restrict__ pk, const float* __restrict__ pv,
                                                   unsigned short* __restrict__ Kf_all,
                                                   unsigned short* __restrict__ Vt_all) {
  int b = blockIdx.y, t0 = blockIdx.x * 64, layer = blockIdx.z, tid = threadIdx.x;
  unsigned short* Kf = Kf_all + (size_t)layer * B_ * TPAD_ * HD_;
  unsigned short* Vt = Vt_all + (size_t)layer * B_ * HD_ * TPAD_;
  __shared__ unsigned short vt[256][72];
  const float* kp = pk + ((size_t)(b * L_ + layer)) * PRE_ * HD_;
  const float* vp = pv + ((size_t)(b * L_ + layer)) * PRE_ * HD_;
  for (int i = 0; i < 64; i++) {
    int t = t0 + i;
    float kv = 0.f, vv = 0.f;
    if (t < PRE_) {
      kv = kp[(size_t)t * HD_ + tid];
      vv = vp[(size_t)t * HD_ + tid];
    }
    Kf[((size_t)b * TPAD_ + t) * HD_ + tid] = f2bf(kv);  // suffix rows rewritten per layer by qkvF
    vt[tid][i] = f2bf(vv);
  }
  __syncthreads();
#pragma unroll
  for (int p = 0; p < 4; p++) {
    int d = p * 64 + (tid >> 2);
    int c0 = (tid & 3) * 16;
    u16x8 v0, v1;
#pragma unroll
    for (int j = 0; j < 8; j++) { v0[j] = vt[d][c0 + j]; v1[j] = vt[d][c0 + 8 + j]; }
    size_t dst = ((size_t)(b * HD_ + d)) * TPAD_ + t0 + c0;
    *(u16x8*)(Vt + dst) = v0;
    *(u16x8*)(Vt + dst + 8) = v1;
  }
}

// ================================================================ QKV GEMM (bf16 A) + RoPE/scatter epilogue
// (validated round-9) grid (80 strips, 2 m-halves), 512 thr.
__global__ __launch_bounds__(512) void qkvF_k(const unsigned short* __restrict__ A,
                                              const float* __restrict__ Wq, const float* __restrict__ Wk,
                                              const float* __restrict__ Wv, const int* __restrict__ offs,
                                              unsigned short* __restrict__ q_r, unsigned short* __restrict__ Kf,
                                              unsigned short* __restrict__ Vt) {
  const int st = blockIdx.x, mh = blockIdx.y;
  const int tid = threadIdx.x, wv = tid >> 6, l = tid & 63;
  const int lr = l & 15, kg = l >> 4, lk = kg << 2;
  const int m0 = mh * 256 + wv * 32;

  const float* W;
  int ldw, wbase;
  bool paired;
  if (st < 64)      { W = Wq; ldw = 2048; wbase = (st >> 3) * 256 + (st & 7) * 16; paired = true; }
  else if (st < 72) { W = Wk; ldw = 256;  wbase = (st - 64) * 16; paired = true; }
  else              { W = Wv; ldw = 256;  wbase = (st - 72) * 32; paired = false; }

  __shared__ unsigned short Wt[2][32][LST_];
  __shared__ int offsL[8];
  const int pr = tid >> 3, c0 = (tid & 7) * 4;
  const int wcol = wbase + c0 + ((paired && c0 >= 16) ? 112 : 0);

  if (tid < 8) offsL[tid] = offs[tid];

  f32x4 acc[2][2];
#pragma unroll
  for (int a = 0; a < 2; a++)
#pragma unroll
    for (int b = 0; b < 2; b++) acc[a][b] = (f32x4){0.f, 0.f, 0.f, 0.f};

  f32x4 pa0, pa1;
  auto LOADW = [&](int IT) {
    size_t kk = (size_t)IT * KSTEP_ + 2 * pr;
    pa0 = *(const f32x4*)(W + kk * ldw + wcol);
    pa1 = *(const f32x4*)(W + (kk + 1) * ldw + wcol);
  };
  auto STOREW = [&](int BUF) {
#pragma unroll
    for (int j = 0; j < 4; j++) {
      unsigned v = (unsigned)f2bf(pa0[j]) | ((unsigned)f2bf(pa1[j]) << 16);
      *(unsigned*)&Wt[BUF][c0 + j][2 * pr] = v;
    }
  };

  LOADW(0);
  STOREW(0);
  __syncthreads();

  for (int it = 0; it < 8; ++it) {
    if (it + 1 < 8) LOADW(it + 1);
    const int cur = it & 1, kb = it * KSTEP_;
#pragma unroll
    for (int s = 0; s < 4; s++) {
      s16x8 bfr[2];
#pragma unroll
      for (int nf = 0; nf < 2; nf++) {
        const unsigned short* wp = &Wt[cur][nf * 16 + lr][s * 32 + 2 * lk];
        s16x4 b0 = *(const s16x4*)wp;
        s16x4 b1 = *(const s16x4*)(wp + 4);
#pragma unroll
        for (int j = 0; j < 4; j++) { bfr[nf][j] = b0[j]; bfr[nf][4 + j] = b1[j]; }
      }
#pragma unroll
      for (int mf = 0; mf < 2; mf++) {
        s16x8 a = *(const s16x8*)(A + (size_t)(m0 + mf * 16 + lr) * H_ + kb + s * 32 + 8 * kg);
#pragma unroll
        for (int nf = 0; nf < 2; nf++)
          acc[mf][nf] = __builtin_amdgcn_mfma_f32_16x16x32_bf16(a, bfr[nf], acc[mf][nf], 0, 0, 0);
      }
    }
    if (it + 1 < 8) STOREW((it + 1) & 1);
    __syncthreads();
  }

  const float RK = -9.210340371976184f / 128.0f;
  if (st < 64) {  // Q: rope pair, write q_r
    const int h = st >> 3, x = (st & 7) * 16, dd = x + lr;
    const float inv = expf((float)dd * RK);
#pragma unroll
    for (int mf = 0; mf < 2; mf++)
#pragma unroll
      for (int r = 0; r < 4; r++) {
        int m = m0 + mf * 16 + lk + r;
        if (m >= MROWS_) continue;
        int b = m / HOR_, s = m - b * HOR_;
        float ang = (float)(offsL[b] + s) * inv;
        float cc = cosf(ang), sn = sinf(ang);
        float v1 = acc[mf][0][r], v2 = acc[mf][1][r];
        size_t base = ((size_t)(b * NH_ + h) * 64 + s) * HD_;
        q_r[base + dd] = f2bf(v1 * cc - v2 * sn);
        q_r[base + dd + 128] = f2bf(v2 * cc + v1 * sn);
      }
  } else if (st < 72) {  // K: rope pair, write Kf suffix rows
    const int x = (st - 64) * 16, dd = x + lr;
    const float inv = expf((float)dd * RK);
#pragma unroll
    for (int mf = 0; mf < 2; mf++)
#pragma unroll
      for (int r = 0; r < 4; r++) {
        int m = m0 + mf * 16 + lk + r;
        if (m >= MROWS_) continue;
        int b = m / HOR_, s = m - b * HOR_;
        float ang = (float)(offsL[b] + s) * inv;
        float cc = cosf(ang), sn = sinf(ang);
        float v1 = acc[mf][0][r], v2 = acc[mf][1][r];
        size_t base = ((size_t)b * TPAD_ + PRE_ + s) * HD_;
        Kf[base + dd] = f2bf(v1 * cc - v2 * sn);
        Kf[base + dd + 128] = f2bf(v2 * cc + v1 * sn);
      }
  } else {  // V: write Vt columns
    const int x = (st - 72) * 32;
#pragma unroll
    for (int mf = 0; mf < 2; mf++)
#pragma unroll
      for (int nf = 0; nf < 2; nf++)
#pragma unroll
        for (int r = 0; r < 4; r++) {
          int m = m0 + mf * 16 + lk + r;
          if (m >= MROWS_) continue;
          int b = m / HOR_, s = m - b * HOR_;
          int d = x + nf * 16 + lr;
          Vt[((size_t)(b * HD_ + d)) * TPAD_ + PRE_ + s] = f2bf(acc[mf][nf][r]);
        }
  }
}

// ================================================================ fused flash attention (validated round-5)
__global__ __launch_bounds__(256) void flashF_k(const unsigned short* __restrict__ qr,
                                                const unsigned short* __restrict__ Kf,
                                                const unsigned short* __restrict__ Vt,
                                                unsigned short* __restrict__ attb) {
  const int rg = blockIdx.x, h = blockIdx.y, b = blockIdx.z;
  const int bh = b * NH_ + h;
  const int tid = threadIdx.x, w = tid >> 6, l = tid & 63;
  const int lr = l & 15, kg = l >> 4;
  const int t0 = w * 256;

  __shared__ union {
    unsigned short P[4][16][264];
    struct { float O[4][16][256]; float ml[4][16][2]; } c;
  } sm;

  f32x4 sc[16];
#pragma unroll
  for (int nf = 0; nf < 16; nf++) sc[nf] = (f32x4){0.f, 0.f, 0.f, 0.f};
  const unsigned short* qbase = qr + ((size_t)bh * 64 + rg * 16 + lr) * HD_;
  const unsigned short* kbase = Kf + ((size_t)b * TPAD_ + t0 + lr) * HD_;
#pragma unroll
  for (int k0 = 0; k0 < HD_; k0 += 32) {
    s16x8 a = *(const s16x8*)(qbase + k0 + 8 * kg);
#pragma unroll
    for (int nf = 0; nf < 16; nf++) {
      s16x8 bv = *(const s16x8*)(kbase + (size_t)nf * 16 * HD_ + k0 + 8 * kg);
      sc[nf] = __builtin_amdgcn_mfma_f32_16x16x32_bf16(a, bv, sc[nf], 0, 0, 0);
    }
  }
  float mx[4] = {-3.0e38f, -3.0e38f, -3.0e38f, -3.0e38f};
#pragma unroll
  for (int nf = 0; nf < 16; nf++) {
    int t = t0 + nf * 16 + lr;
#pragma unroll
    for (int r = 0; r < 4; r++) {
      int row = rg * 16 + 4 * kg + r;
      float v = sc[nf][r] * 0.0625f;
      if (t >= PRE_ && (t - PRE_) > row) v = -1e9f;
      sc[nf][r] = v;
      mx[r] = fmaxf(mx[r], v);
    }
  }
#pragma unroll
  for (int o = 8; o > 0; o >>= 1)
#pragma unroll
    for (int r = 0; r < 4; r++) mx[r] = fmaxf(mx[r], __shfl_xor(mx[r], o));
  float ls[4] = {0.f, 0.f, 0.f, 0.f};
#pragma unroll
  for (int nf = 0; nf < 16; nf++)
#pragma unroll
    for (int r = 0; r < 4; r++) {
      float p = expf(sc[nf][r] - mx[r]);
      sc[nf][r] = p;
      ls[r] += p;
    }
#pragma unroll
  for (int o = 8; o > 0; o >>= 1)
#pragma unroll
    for (int r = 0; r < 4; r++) ls[r] += __shfl_xor(ls[r], o);
#pragma unroll
  for (int nf = 0; nf < 16; nf++)
#pragma unroll
    for (int r = 0; r < 4; r++) sm.P[w][4 * kg + r][nf * 16 + lr] = f2bf(sc[nf][r]);
  __syncthreads();
  f32x4 o4[16];
#pragma unroll
  for (int nf = 0; nf < 16; nf++) o4[nf] = (f32x4){0.f, 0.f, 0.f, 0.f};
  const unsigned short* vbase = Vt + ((size_t)(b * HD_ + lr)) * TPAD_ + t0;
#pragma unroll
  for (int ti = 0; ti < 256; ti += 32) {
    s16x8 a = *(const s16x8*)&sm.P[w][lr][ti + 8 * kg];
#pragma unroll
    for (int nf = 0; nf < 16; nf++) {
      s16x8 bv = *(const s16x8*)(vbase + (size_t)nf * 16 * TPAD_ + ti + 8 * kg);
      o4[nf] = __builtin_amdgcn_mfma_f32_16x16x32_bf16(a, bv, o4[nf], 0, 0, 0);
    }
  }
  __syncthreads();
#pragma unroll
  for (int nf = 0; nf < 16; nf++)
#pragma unroll
    for (int r = 0; r < 4; r++) sm.c.O[w][4 * kg + r][nf * 16 + lr] = o4[nf][r];
  if (lr == 0) {
#pragma unroll
    for (int r = 0; r < 4; r++) {
      sm.c.ml[w][4 * kg + r][0] = mx[r];
      sm.c.ml[w][4 * kg + r][1] = ls[r];
    }
  }
  __syncthreads();
#pragma unroll
  for (int row = 0; row < 16; row++) {
    int s = rg * 16 + row;
    if (s >= HOR_) break;
    float M = -3.0e38f;
#pragma unroll
    for (int z = 0; z < 4; z++) M = fmaxf(M, sm.c.ml[z][row][0]);
    float den = 0.f, o = 0.f;
#pragma unroll
    for (int z = 0; z < 4; z++) {
      float wz = expf(sm.c.ml[z][row][0] - M);
      den += wz * sm.c.ml[z][row][1];
      o += wz * sm.c.O[z][row][tid];
    }
    attb[((size_t)(b * HOR_ + s)) * 2048 + h * HD_ + tid] = f2bf(o / den);
  }
}

// ================================================================ split-K MFMA GEMM stage 1 (validated round-5)
// MODE 1=WO, 2=UPGATE(dual; t=gelu(g)*u bf16), 3=DOWN. NS=K-split, MS=M-split. 512 thr.
template <int MODE, int NS, int MS>
__global__ __launch_bounds__(512) void gemmS_k(const unsigned short* __restrict__ A, int lda, int Ksz,
                                               const float* __restrict__ W0, const float* __restrict__ W1,
                                               float* __restrict__ part, unsigned short* __restrict__ outT) {
  constexpr int NCOL = (MODE == 2) ? 64 : 32;
  constexpr int NF = NCOL / 16;
  constexpr int RPW = 64 / MS;
  constexpr int MFC = RPW / 16;
  const int tid = threadIdx.x;
  const int wv = tid >> 6, l = tid & 63;
  const int lr = l & 15, lk = (l >> 4) << 2;
  const int n0 = blockIdx.x * 32;
  const int kz = blockIdx.y;
  const int KC = Ksz / NS;
  const int kbase = kz * KC;
  const int m0 = (int)blockIdx.z * (512 / MS) + wv * RPW;

  const float* Wg = W0;
  const float* Wu = W1;
  const int ldw = (MODE == 2) ? 4096 : 1024;

  __shared__ unsigned short Wt[2][NCOL][LST_];
  const int pr = tid >> 3;
  const int c0 = (tid & 7) * 4;

  f32x4 acc[MFC][NF];
#pragma unroll
  for (int a = 0; a < MFC; a++)
#pragma unroll
    for (int b = 0; b < NF; b++) acc[a][b] = (f32x4){0.f, 0.f, 0.f, 0.f};

  const int niter = KC / KSTEP_;
  f32x4 pa0, pa1, pb0, pb1;

  auto LOADW = [&](int IT) {
    size_t kk = (size_t)(kbase + IT * KSTEP_ + 2 * pr);
    pa0 = *(const f32x4*)(Wg + kk * ldw + n0 + c0);
    pa1 = *(const f32x4*)(Wg + (kk + 1) * ldw + n0 + c0);
    if (MODE == 2) {
      pb0 = *(const f32x4*)(Wu + kk * ldw + n0 + c0);
      pb1 = *(const f32x4*)(Wu + (kk + 1) * ldw + n0 + c0);
    }
  };
  auto STOREW = [&](int BUF) {
#pragma unroll
    for (int j = 0; j < 4; j++) {
      unsigned v = (unsigned)f2bf(pa0[j]) | ((unsigned)f2bf(pa1[j]) << 16);
      *(unsigned*)&Wt[BUF][c0 + j][2 * pr] = v;
      if (MODE == 2) {
        unsigned u = (unsigned)f2bf(pb0[j]) | ((unsigned)f2bf(pb1[j]) << 16);
        *(unsigned*)&Wt[BUF][32 + c0 + j][2 * pr] = u;
      }
    }
  };

  LOADW(0);
  STOREW(0);
  __syncthreads();

  for (int it = 0; it < niter; ++it) {
    if (it + 1 < niter) LOADW(it + 1);
    const int cur = it & 1;
    const int kb = kbase + it * KSTEP_;
#pragma unroll
    for (int s = 0; s < 4; s++) {
      s16x8 bfr[NF];
#pragma unroll
      for (int nf = 0; nf < NF; nf++) {
        const unsigned short* wp = &Wt[cur][nf * 16 + lr][s * 32 + 2 * lk];
        s16x4 b0 = *(const s16x4*)wp;
        s16x4 b1 = *(const s16x4*)(wp + 4);
#pragma unroll
        for (int j = 0; j < 4; j++) { bfr[nf][j] = b0[j]; bfr[nf][4 + j] = b1[j]; }
      }
#pragma unroll
      for (int mf = 0; mf < MFC; mf++) {
        s16x8 a = *(const s16x8*)(A + (size_t)(m0 + mf * 16 + lr) * lda + kb + s * 32 + 2 * lk);
#pragma unroll
        for (int nf = 0; nf < NF; nf++)
          acc[mf][nf] = __builtin_amdgcn_mfma_f32_16x16x32_bf16(a, bfr[nf], acc[mf][nf], 0, 0, 0);
      }
    }
    if (it + 1 < niter) STOREW((it + 1) & 1);
    __syncthreads();
  }

  if (MODE == 2) {
#pragma unroll
    for (int mf = 0; mf < MFC; mf++)
#pragma unroll
      for (int nf = 0; nf < 2; nf++)
#pragma unroll
        for (int r = 0; r < 4; r++) {
          int row = m0 + mf * 16 + lk + r;
          if (row >= MROWS_) continue;
          int col = n0 + nf * 16 + lr;
          float g = acc[mf][nf][r];
          float u = acc[mf][nf + 2][r];
          g = 0.5f * g * (1.f + tanhf(0.7978845608028654f * (g + 0.044715f * g * g * g)));
          outT[(size_t)row * 4096 + col] = f2bf(g * u);
        }
  } else {
#pragma unroll
    for (int mf = 0; mf < MFC; mf++)
#pragma unroll
      for (int nf = 0; nf < NF; nf++)
#pragma unroll
        for (int r = 0; r < 4; r++) {
          int row = m0 + mf * 16 + lk + r;
          if (row >= MROWS_) continue;
          int col = n0 + nf * 16 + lr;
          part[((size_t)kz * MPAD_ + row) * 1024 + col] = acc[mf][nf][r];
        }
  }
}

// ---------------------------------------------------------------- split-K reduce + residual-gate + AdaRMSNorm
template <int NS>
__global__ __launch_bounds__(256) void redA_k(const float* __restrict__ part, const float* __restrict__ prev,
                                              const float* __restrict__ gatev, const float* __restrict__ nw,
                                              const float* __restrict__ sc, float* __restrict__ outH,
                                              unsigned short* __restrict__ outN) {
  int r = blockIdx.x, tid = threadIdx.x;
  int c = tid * 4;
  f32x4 h = (f32x4){0.f, 0.f, 0.f, 0.f};
  int b = 0;
  if (r < MROWS_) {
    b = r / HOR_;
    f32x4 v = (f32x4){0.f, 0.f, 0.f, 0.f};
#pragma unroll
    for (int z = 0; z < NS; z++) v += *(const f32x4*)(part + ((size_t)z * MPAD_ + r) * H_ + c);
    f32x4 pv = *(const f32x4*)(prev + (size_t)r * H_ + c);
    f32x4 gv = *(const f32x4*)(gatev + (size_t)b * H_ + c);
    h = pv + gv * v;
  }
  *(f32x4*)(outH + (size_t)r * H_ + c) = h;
  float ss = h[0] * h[0] + h[1] * h[1] + h[2] * h[2] + h[3] * h[3];
  __shared__ float r4[4];
  float wsv = wave_sum(ss);
  if ((tid & 63) == 0) r4[tid >> 6] = wsv;
  __syncthreads();
  float rs = rsqrtf((r4[0] + r4[1] + r4[2] + r4[3]) * (1.f / 1024.f) + 1e-6f);
#pragma unroll
  for (int j = 0; j < 4; j++) {
    int n = c + j;
    outN[(size_t)r * H_ + n] = f2bf(h[j] * rs * (1.f + nw[n]) * (1.f + sc[(size_t)b * H_ + n]));
  }
}

// ---------------------------------------------------------------- out = normedF @ action_out_w + b
__global__ __launch_bounds__(256) void fout_k(const unsigned short* __restrict__ nf, const float* __restrict__ Wo,
                                              const float* __restrict__ bo, float* __restrict__ out) {
  int m = blockIdx.x, tid = threadIdx.x;
  int n = tid & 31, kg = tid >> 5;
  float acc = 0.f;
  for (int k = kg * 128; k < kg * 128 + 128; k++)
    acc += bf2f(nf[(size_t)m * H_ + k]) * Wo[(size_t)k * AD_ + n];
  __shared__ float red[8][32];
  red[kg][n] = acc;
  __syncthreads();
  if (kg == 0) {
    float v = 0.f;
#pragma unroll
    for (int g = 0; g < 8; g++) v += red[g][n];
    out[(size_t)m * AD_ + n] = v + bo[n];
  }
}

// ================================================================ host
extern "C" void kernel_launch(void* const* d_in, const int* in_sizes, int n_in,
                              void* d_out, int out_size, void* d_ws, size_t ws_size,
                              hipStream_t stream) {
  const float* prefix_keys   = (const float*)d_in[0];
  const float* prefix_values = (const float*)d_in[1];
  const float* x_t           = (const float*)d_in[2];
  const float* timestep      = (const float*)d_in[3];
  const unsigned char* pad_mask = (const unsigned char*)d_in[4];
  const float* action_in_w   = (const float*)d_in[5];
  const float* action_in_b   = (const float*)d_in[6];
  const float* action_out_w  = (const float*)d_in[7];
  const float* action_out_b  = (const float*)d_in[8];
  const float* tmlp_in_w     = (const float*)d_in[9];
  const float* tmlp_in_b     = (const float*)d_in[10];
  const float* tmlp_out_w    = (const float*)d_in[11];
  const float* tmlp_out_b    = (const float*)d_in[12];
  const float* w_q    = (const float*)d_in[13];
  const float* w_k    = (const float*)d_in[14];
  const float* w_v    = (const float*)d_in[15];
  const float* w_o    = (const float*)d_in[16];
  const float* w_gate = (const float*)d_in[17];
  const float* w_up   = (const float*)d_in[18];
  const float* w_down = (const float*)d_in[19];
  const float* in_norm_w    = (const float*)d_in[20];
  const float* in_scale_w   = (const float*)d_in[21];
  const float* in_gate_w    = (const float*)d_in[22];
  const float* post_norm_w  = (const float*)d_in[23];
  const float* post_scale_w = (const float*)d_in[24];
  const float* post_gate_w  = (const float*)d_in[25];
  const float* fnorm_w       = (const float*)d_in[26];
  const float* fnorm_scale_w = (const float*)d_in[27];

  char* wsp = (char*)d_ws;
  auto alloc = [&](size_t bytes) { void* p = (void*)wsp; wsp += (bytes + 255) & ~(size_t)255; return p; };

  float* emb0   = (float*)alloc((size_t)8 * H_ * 4);
  float* emb1   = (float*)alloc((size_t)8 * H_ * 4);
  float* cond   = (float*)alloc((size_t)8 * H_ * 4);
  float* fscale = (float*)alloc((size_t)8 * H_ * 4);
  float* gates  = (float*)alloc((size_t)4 * L_ * 8 * H_ * 4);
  int*   offs   = (int*)alloc(64);
  float* hbuf   = (float*)alloc((size_t)MPAD_ * H_ * 4);
  float* h1buf  = (float*)alloc((size_t)MPAD_ * H_ * 4);
  unsigned short* normed  = (unsigned short*)alloc((size_t)MPAD_ * H_ * 2);
  unsigned short* normed2 = (unsigned short*)alloc((size_t)MPAD_ * H_ * 2);
  unsigned short* q_r     = (unsigned short*)alloc((size_t)B_ * NH_ * 64 * HD_ * 2);
  unsigned short* Kf_all  = (unsigned short*)alloc((size_t)L_ * B_ * TPAD_ * HD_ * 2);
  unsigned short* Vt_all  = (unsigned short*)alloc((size_t)L_ * B_ * HD_ * TPAD_ * 2);
  unsigned short* attb    = (unsigned short*)alloc((size_t)MPAD_ * 2048 * 2);
  unsigned short* t_buf   = (unsigned short*)alloc((size_t)MPAD_ * FF_ * 2);
  float* wopart = (float*)alloc((size_t)4 * MPAD_ * 1024 * 4);
  float* dpart  = (float*)alloc((size_t)4 * MPAD_ * 1024 * 4);

  // attb pad rows never written by flashF: zero once (stays zero all layers)
  hipMemsetAsync(attb + (size_t)MROWS_ * 2048, 0, (size_t)(MPAD_ - MROWS_) * 2048 * 2, stream);

  emb_k<<<8, 256, 0, stream>>>(timestep, emb0);
  gemm8_k<<<16, 256, 0, stream>>>(emb0, tmlp_in_w, tmlp_in_b, emb1, 1);
  gemm8_k<<<16, 256, 0, stream>>>(emb1, tmlp_out_w, tmlp_out_b, cond, 1);
  gemm8_k<<<16, 256, 0, stream>>>(cond, fnorm_scale_w, nullptr, fscale, 0);
  gates_k<<<dim3(16, L_, 4), 256, 0, stream>>>(cond, in_scale_w, in_gate_w, post_scale_w, post_gate_w, gates);
  offs_k<<<1, 256, 0, stream>>>(pad_mask, offs);
  action_in_k<<<(MPAD_ * H_) / 256, 256, 0, stream>>>(x_t, action_in_w, action_in_b, hbuf);
  prefixAll_k<<<dim3(16, B_, L_), 256, 0, stream>>>(prefix_keys, prefix_values, Kf_all, Vt_all);
  ada_k<<<MPAD_, 256, 0, stream>>>(hbuf, in_norm_w, gates, normed);  // layer-0 in_scale = gates z=0,l=0

  for (int i = 0; i < L_; i++) {
    const float* wq_i = w_q + (size_t)i * H_ * 2048;
    const float* wk_i = w_k + (size_t)i * H_ * HD_;
    const float* wv_i = w_v + (size_t)i * H_ * HD_;
    const float* wo_i = w_o + (size_t)i * 2048 * H_;
    const float* wg_i = w_gate + (size_t)i * H_ * FF_;
    const float* wu_i = w_up + (size_t)i * H_ * FF_;
    const float* wd_i = w_down + (size_t)i * FF_ * H_;
    const float* g_in_gate    = gates + ((size_t)(1 * L_ + i) * 8) * H_;
    const float* g_post_scale = gates + ((size_t)(2 * L_ + i) * 8) * H_;
    const float* g_post_gate  = gates + ((size_t)(3 * L_ + i) * 8) * H_;
    unsigned short* Kf_l = Kf_all + (size_t)i * B_ * TPAD_ * HD_;
    unsigned short* Vt_l = Vt_all + (size_t)i * B_ * HD_ * TPAD_;

    qkvF_k<<<dim3(80, 2), 512, 0, stream>>>(normed, wq_i, wk_i, wv_i, offs, q_r, Kf_l, Vt_l);
    flashF_k<<<dim3(4, NH_, B_), 256, 0, stream>>>(q_r, Kf_l, Vt_l, attb);
    gemmS_k<1, 4, 2><<<dim3(32, 4, 2), 512, 0, stream>>>(attb, 2048, 2048, wo_i, nullptr, wopart, nullptr);
    redA_k<4><<<MPAD_, 256, 0, stream>>>(wopart, hbuf, g_in_gate, post_norm_w + (size_t)i * H_,
                                         g_post_scale, h1buf, normed2);
    gemmS_k<2, 1, 2><<<dim3(128, 1, 2), 512, 0, stream>>>(normed2, H_, H_, wg_i, wu_i, nullptr, t_buf);
    gemmS_k<3, 4, 2><<<dim3(32, 4, 2), 512, 0, stream>>>(t_buf, FF_, FF_, wd_i, nullptr, dpart, nullptr);
    const float* nw_next = (i + 1 < L_) ? in_norm_w + (size_t)(i + 1) * H_ : fnorm_w;
    const float* sc_next = (i + 1 < L_) ? gates + ((size_t)(i + 1) * 8) * H_ : fscale;
    redA_k<4><<<MPAD_, 256, 0, stream>>>(dpart, h1buf, g_post_gate, nw_next, sc_next, hbuf, normed);
  }

  fout_k<<<MROWS_, 256, 0, stream>>>(normed, action_out_w, action_out_b, (float*)d_out);
}